// Round 8
// baseline (2512.518 us; speedup 1.0000x reference)
//
#include <hip/hip_runtime.h>

typedef unsigned short u16;
typedef unsigned char u8;
typedef float f32x4 __attribute__((ext_vector_type(4)));
typedef int i32x4 __attribute__((ext_vector_type(4)));
typedef int i32x8 __attribute__((ext_vector_type(8)));
typedef u16 u16x4 __attribute__((ext_vector_type(4)));

#define N_FEAT 8192
#define M_MEM 16384
#define C_DIM 1536
#define NBATCH 32
#define NKT 12            // 1536/128 K-tiles (BK=128, fp8)
#define NMT 128           // 16384/128 memory tiles
#define FINF 3.4e38f
#define BAND 0.15f

__device__ __forceinline__ unsigned f2fp8(float x){     // fp32 -> OCP e4m3fn RTNE
  unsigned u = __float_as_uint(x);
  unsigned s = (u >> 24) & 0x80u;
  float a = fabsf(x);
  if (a >= 448.f) return s | 0x7Eu;
  if (a < 0.015625f){                  // < 2^-6: denormal (step 2^-9), 8 == min normal
    int n = (int)rintf(a * 512.f);
    return s | (unsigned)n;
  }
  unsigned b = __float_as_uint(a);
  b += 0x7FFFFu + ((b >> 20) & 1u);    // RTNE into 3-bit mantissa
  int e = (int)(b >> 23) - 127;
  if (e > 8) return s | 0x7Eu;
  return s | (unsigned)(((e + 7) << 3) | ((b >> 20) & 7u));
}

#define GLDS16(g, l) __builtin_amdgcn_global_load_lds( \
    (const __attribute__((address_space(1))) void*)(g), \
    (__attribute__((address_space(3))) void*)(l), 16, 0, 0)

__device__ __forceinline__ bool ltpair(float va, int ia, float vb, int ib){
  return va < vb || (va == vb && ia < ib);
}

// ---------------------------------------------------------------------------
// 1) fp32 -> fp8 e4m3 copy + exact fp32 row norms. 1 wave/row, 4 rows/block.
// ---------------------------------------------------------------------------
__global__ __launch_bounds__(256) void conv_norm_k(const float* __restrict__ in,
                                                   u8* __restrict__ ob,
                                                   float* __restrict__ nrm){
  int row  = blockIdx.x*4 + (threadIdx.x>>6);
  int lane = threadIdx.x & 63;
  const float* r = in + (size_t)row*C_DIM;
  u8* o = ob + (size_t)row*C_DIM;
  float s = 0.f;
  #pragma unroll
  for (int i=0;i<6;++i){
    int idx = i*256 + lane*4;
    float4 v = *(const float4*)(r + idx);
    s += v.x*v.x + v.y*v.y + v.z*v.z + v.w*v.w;
    unsigned pk = f2fp8(v.x) | (f2fp8(v.y)<<8) | (f2fp8(v.z)<<16) | (f2fp8(v.w)<<24);
    *(unsigned*)(o + idx) = pk;
  }
  #pragma unroll
  for (int m=32;m;m>>=1) s += __shfl_xor(s, m);
  if (lane==0) nrm[row] = s;
}

// ---------------------------------------------------------------------------
// 2) 128x128 MX-fp8 MFMA distance (K=128/inst, unit scales) + fused per-row
//    TOP-2 min/argmin per tile. m97 structure: 4 waves (2x2, 64x64 out), one
//    32 KiB LDS buffer, __syncthreads sync, no launch-bounds min.
//    LDS k-major [kg32][sub16][row][16B]: linear staging, contiguous reads.
// ---------------------------------------------------------------------------
__global__ __launch_bounds__(256) void dist_fp8_k(const u8* __restrict__ fb,
                                                  const u8* __restrict__ mb,
                                                  const float* __restrict__ fn,
                                                  const float* __restrict__ mn,
                                                  float* __restrict__ pv1,
                                                  int* __restrict__ pi1,
                                                  float* __restrict__ pv2,
                                                  int* __restrict__ pi2){
  __shared__ u8 lds[32768];           // A 16K (4 kg x 2 sub x 128 row x 16B) + B 16K
  const int tid = threadIdx.x;
  const int bid = blockIdx.x;
  // bijective XCD remap: 16 mt x 4-nt groups per XCD
  const int xcd = bid & 7;
  const int li  = bid >> 3;                     // 0..1023
  const int nt  = ((li >> 6) << 2) | (li & 3);  // 0..63 feature tile
  const int mt  = (xcd << 4) | ((li >> 2) & 15);// 0..127 memory tile
  const int wid = tid >> 6, lane = tid & 63;
  const int wm = wid >> 1, wn = wid & 1;        // 2x2 waves, each 64x64 out
  const int lr = lane & 15, lk = lane >> 4;
  const int arow0 = nt*128, brow0 = mt*128;

  // issue kg block: 4 KiB = 2 sub x 128 rows x 16B, dest linear in tid
#define ISSUE_A(kt, kg) GLDS16( \
    fb + (size_t)(arow0 + (tid&127))*C_DIM + (kt)*128 + (kg)*32 + (tid>>7)*16, \
    lds + (kg)*4096 + tid*16)
#define ISSUE_B(kt, kg) GLDS16( \
    mb + (size_t)(brow0 + (tid&127))*C_DIM + (kt)*128 + (kg)*32 + (tid>>7)*16, \
    lds + 16384 + (kg)*4096 + tid*16)
  // lane frag: row in [0,128), k-group = lk; lo = sub0 (k+0..15), hi = sub1
#define LDA_LO(row) (*(const i32x4*)(lds + lk*4096        + (row)*16))
#define LDA_HI(row) (*(const i32x4*)(lds + lk*4096 + 2048 + (row)*16))
#define LDB_LO(row) (*(const i32x4*)(lds + 16384 + lk*4096        + (row)*16))
#define LDB_HI(row) (*(const i32x4*)(lds + 16384 + lk*4096 + 2048 + (row)*16))

  f32x4 acc[4][4];
  #pragma unroll
  for (int m=0;m<4;++m)
    #pragma unroll
    for (int n=0;n<4;++n) acc[m][n] = (f32x4){0.f,0.f,0.f,0.f};

  const int sc1 = 0x7F7F7F7F;         // e8m0 = 127 -> scale 1.0 (byte0 via opsel 0)

  for (int u=0; u<NKT; ++u){
    ISSUE_A(u,0); ISSUE_A(u,1); ISSUE_A(u,2); ISSUE_A(u,3);
    ISSUE_B(u,0); ISSUE_B(u,1); ISSUE_B(u,2); ISSUE_B(u,3);
    __syncthreads();                  // drains vmcnt + barrier
    i32x8 bv[4];
    #pragma unroll
    for (int n=0;n<4;++n){
      i32x4 lo = LDB_LO(wn*64 + n*16 + lr);
      i32x4 hi = LDB_HI(wn*64 + n*16 + lr);
      bv[n] = __builtin_shufflevector(lo, hi, 0,1,2,3,4,5,6,7);
    }
    #pragma unroll
    for (int m=0;m<4;++m){
      i32x4 lo = LDA_LO(wm*64 + m*16 + lr);
      i32x4 hi = LDA_HI(wm*64 + m*16 + lr);
      i32x8 av = __builtin_shufflevector(lo, hi, 0,1,2,3,4,5,6,7);
      #pragma unroll
      for (int n=0;n<4;++n)
        acc[m][n] = __builtin_amdgcn_mfma_scale_f32_16x16x128_f8f6f4(
                      av, bv[n], acc[m][n], 0, 0, 0, sc1, 0, sc1);
    }
    __syncthreads();                  // frag reads done before next overwrite
  }

  // epilogue: d = sqrt(max(fa + mb - 2ab, 0)); per-row TOP-2 over 128 cols.
  // C/D frag layout: col = lane&15, row = (lane>>4)*4 + reg (shape-determined)
  const int rowbase = nt*128 + wm*64;
  const int colbase = mt*128 + wn*64;
  float mnv[4];
  #pragma unroll
  for (int n=0;n<4;++n) mnv[n] = mn[colbase + n*16 + lr];
  float* s1 = (float*)lds;                     // [2][128]
  int*   s2 = (int*)  (lds + 1024);
  float* s3 = (float*)(lds + 2048);
  int*   s4 = (int*)  (lds + 3072);
  #pragma unroll
  for (int m=0;m<4;++m){
    float v1[4], v2[4]; int i1[4], i2[4];
    #pragma unroll
    for (int r=0;r<4;++r){
      float fa = fn[rowbase + m*16 + lk*4 + r];
      v1[r]=FINF; i1[r]=0x7fffffff; v2[r]=FINF; i2[r]=0x7fffffff;
      #pragma unroll
      for (int n=0;n<4;++n){
        int ci = colbase + n*16 + lr;
        float d = sqrtf(fmaxf(fa + mnv[n] - 2.0f*acc[m][n][r], 0.0f));
        if (ltpair(d,ci, v1[r],i1[r])){ v2[r]=v1[r]; i2[r]=i1[r]; v1[r]=d; i1[r]=ci; }
        else if (ltpair(d,ci, v2[r],i2[r])){ v2[r]=d; i2[r]=ci; }
      }
    }
    #pragma unroll
    for (int msk=1; msk<16; msk<<=1){
      #pragma unroll
      for (int r=0;r<4;++r){
        float ov1=__shfl_xor(v1[r],msk), ov2=__shfl_xor(v2[r],msk);
        int   oi1=__shfl_xor(i1[r],msk), oi2=__shfl_xor(i2[r],msk);
        if (ltpair(ov1,oi1, v1[r],i1[r])){
          if (ltpair(v1[r],i1[r], ov2,oi2)){ v2[r]=v1[r]; i2[r]=i1[r]; }
          else { v2[r]=ov2; i2[r]=oi2; }
          v1[r]=ov1; i1[r]=oi1;
        } else if (ltpair(ov1,oi1, v2[r],i2[r])){ v2[r]=ov1; i2[r]=oi1; }
      }
    }
    if (lr == 0){
      #pragma unroll
      for (int r=0;r<4;++r){
        int rl = wm*64 + m*16 + lk*4 + r;
        s1[wn*128+rl]=v1[r]; s2[wn*128+rl]=i1[r];
        s3[wn*128+rl]=v2[r]; s4[wn*128+rl]=i2[r];
      }
    }
  }
  __syncthreads();
  if (tid < 128){
    float a1=s1[tid], a2=s3[tid], b1=s1[128+tid], b2=s3[128+tid];
    int   ai1=s2[tid], ai2=s4[tid], bi1=s2[128+tid], bi2=s4[128+tid];
    float v1,v2; int i1,i2;
    if (ltpair(a1,ai1,b1,bi1)){
      v1=a1; i1=ai1;
      if (ltpair(b1,bi1,a2,ai2)){ v2=b1; i2=bi1; } else { v2=a2; i2=ai2; }
    } else {
      v1=b1; i1=bi1;
      if (ltpair(a1,ai1,b2,bi2)){ v2=a1; i2=ai1; } else { v2=b2; i2=bi2; }
    }
    size_t o = (size_t)(nt*128 + tid)*NMT + mt;
    pv1[o]=v1; pi1[o]=i1; pv2[o]=v2; pi2[o]=i2;
  }
#undef ISSUE_A
#undef ISSUE_B
#undef LDA_LO
#undef LDA_HI
#undef LDB_LO
#undef LDB_HI
}

// ---------------------------------------------------------------------------
// 3) refine: exact fp32 distance for top-1/top-2 candidates within band of
//    fp8 min -> exact nn_dists / nn_indices (selection-exact vs reference).
// ---------------------------------------------------------------------------
__global__ __launch_bounds__(256) void refine_k(const float* __restrict__ feat,
                                                const float* __restrict__ memf,
                                                const float* __restrict__ fn,
                                                const float* __restrict__ mn,
                                                const float* __restrict__ pv1,
                                                const int* __restrict__ pi1,
                                                const float* __restrict__ pv2,
                                                const int* __restrict__ pi2,
                                                float* __restrict__ nnd,
                                                int* __restrict__ nni){
  int wid = threadIdx.x>>6, lane = threadIdx.x&63;
  int row = blockIdx.x*4 + wid;
  const float* pm1 = pv1 + (size_t)row*NMT;
  const float* pm2 = pv2 + (size_t)row*NMT;
  const int*   px1 = pi1 + (size_t)row*NMT;
  const int*   px2 = pi2 + (size_t)row*NMT;
  float a1 = pm1[lane], a2 = pm1[64+lane];
  float c1 = pm2[lane], c2 = pm2[64+lane];
  float mv = fminf(a1, a2);
  #pragma unroll
  for (int m=32;m;m>>=1) mv = fminf(mv, __shfl_xor(mv, m));
  float band = mv + BAND;   // 11 sigma of fp8-GEMM distance error
  unsigned long long b0 = __ballot(a1 <= band);
  unsigned long long b1 = __ballot(a2 <= band);
  unsigned long long b2 = __ballot(c1 <= band);
  unsigned long long b3 = __ballot(c2 <= band);

  float fr[24];
  const float* f = feat + (size_t)row*C_DIM;
  #pragma unroll
  for (int i=0;i<6;++i){
    float4 t = *(const float4*)(f + i*256 + lane*4);
    fr[i*4+0]=t.x; fr[i*4+1]=t.y; fr[i*4+2]=t.z; fr[i*4+3]=t.w;
  }
  float fa = fn[row];
  float bd = FINF; int bi = 0x7fffffff;
  while (b0 | b1 | b2 | b3){
    int cidx;
    if (b0){ int t=__ffsll(b0)-1; b0&=b0-1; cidx=px1[t]; }
    else if (b1){ int t=__ffsll(b1)-1; b1&=b1-1; cidx=px1[64+t]; }
    else if (b2){ int t=__ffsll(b2)-1; b2&=b2-1; cidx=px2[t]; }
    else { int t=__ffsll(b3)-1; b3&=b3-1; cidx=px2[64+t]; }
    const float* mrow = memf + (size_t)cidx*C_DIM;
    float acc = 0.f;
    #pragma unroll
    for (int i=0;i<6;++i){
      float4 m4 = *(const float4*)(mrow + i*256 + lane*4);
      acc += fr[i*4+0]*m4.x + fr[i*4+1]*m4.y + fr[i*4+2]*m4.z + fr[i*4+3]*m4.w;
    }
    #pragma unroll
    for (int m=32;m;m>>=1) acc += __shfl_xor(acc, m);
    float d = sqrtf(fmaxf(fa + mn[cidx] - 2.0f*acc, 0.f));
    if (d < bd || (d == bd && cidx < bi)){ bd = d; bi = cidx; }
  }
  if (lane==0){ nnd[row]=bd; nni[row]=bi; }
}

// ---------------------------------------------------------------------------
// 4) WT[i][y] = composite (gaussian-zero-pad o bilinear-halfpixel) weights
// ---------------------------------------------------------------------------
__global__ void build_WT(float* __restrict__ WT){
  int y = threadIdx.x;                 // 256 threads, 1 block
  float g[25]; float Z = 0.f;
  #pragma unroll
  for (int k=0;k<25;++k){ float x=(float)(k-12)*0.25f; g[k]=expf(-0.5f*x*x); Z+=g[k]; }
  float acc[16];
  #pragma unroll
  for (int i=0;i<16;++i) acc[i]=0.f;
  for (int dy=0; dy<25; ++dy){
    int yy = y - 12 + dy;
    if (yy < 0 || yy > 255) continue;
    float gg = g[dy]/Z;
    float src = ((float)yy + 0.5f)*0.0625f - 0.5f;
    int i0 = (int)floorf(src);
    float fz = src - (float)i0;
    if (i0 < 0){ i0 = 0; fz = 0.f; }
    else if (i0 >= 15){ i0 = 15; fz = 0.f; }
    acc[i0] += gg*(1.f-fz);
    if (fz > 0.f) acc[i0+1] += gg*fz;
  }
  for (int i=0;i<16;++i) WT[i*256 + y] = acc[i];
}

// ---------------------------------------------------------------------------
// 5) amap[b] = W ps[b] W^T  (separable; exact fp32)
// ---------------------------------------------------------------------------
__global__ __launch_bounds__(256) void amap_k(const float* __restrict__ nnd,
                                              const float* __restrict__ WT,
                                              float* __restrict__ out){
  __shared__ float ps[256];
  __shared__ float wt[16*256];
  __shared__ float tmp[16*256];
  int b = blockIdx.x, yc = blockIdx.y, t = threadIdx.x;
  ps[t] = nnd[b*256 + t];
  #pragma unroll
  for (int i=0;i<16;++i) wt[i*256+t] = WT[i*256+t];
  __syncthreads();
  #pragma unroll
  for (int i=0;i<16;++i){
    float s=0.f;
    #pragma unroll
    for (int j=0;j<16;++j) s += wt[j*256+t]*ps[i*16+j];
    tmp[i*256+t]=s;
  }
  __syncthreads();
  float* ob = out + ((size_t)b<<16) + yc*32*256 + t;
  for (int yy=0; yy<32; ++yy){
    int y = yc*32+yy;
    float s=0.f;
    #pragma unroll
    for (int i=0;i<16;++i) s += wt[i*256+y]*tmp[i*256+t];
    ob[(size_t)yy*256] = s;
  }
}

// ---------------------------------------------------------------------------
// 6) per-batch argmax of patch scores -> s_star, m_star_idx
// ---------------------------------------------------------------------------
__global__ void argmax_k(const float* __restrict__ nnd, const int* __restrict__ nni,
                         float* __restrict__ sstar, int* __restrict__ midx){
  int b=blockIdx.x, t=threadIdx.x, lane=t&63, wid=t>>6;
  float v = nnd[b*256+t]; int i=t;
  #pragma unroll
  for (int m=1;m<64;m<<=1){
    float ov=__shfl_xor(v,m); int oi=__shfl_xor(i,m);
    if (ov > v || (ov==v && oi<i)){ v=ov; i=oi; }
  }
  __shared__ float sv[4]; __shared__ int si[4];
  if (lane==0){ sv[wid]=v; si[wid]=i; }
  __syncthreads();
  if (t==0){
    for (int w=1;w<4;++w){ if (sv[w]>v || (sv[w]==v && si[w]<i)){ v=sv[w]; i=si[w]; } }
    sstar[b]=v; midx[b]=nni[b*256+i];
  }
}

// ---------------------------------------------------------------------------
// 7) m_dists: 32 m_star vectors (fp32, 8 staged in LDS per pass) vs all rows
// ---------------------------------------------------------------------------
__global__ __launch_bounds__(256) void mdist_k(const float* __restrict__ memf,
                                               const float* __restrict__ mn,
                                               const int* __restrict__ midx,
                                               float* __restrict__ dmat){
  __shared__ float ms[8][C_DIM];     // 48 KiB: 8 m_star rows per pass
  __shared__ int sidx[32]; __shared__ float snrm[32];
  int t = threadIdx.x;
  if (t < 32){ int r = midx[t]; sidx[t]=r; snrm[t]=mn[r]; }
  int wid=t>>6, lane=t&63;
  for (int h=0; h<4; ++h){
    __syncthreads();
    for (int c=t; c<3072; c+=256){     // 8 rows x 384 float4 chunks
      int s = c/384, o = c - s*384;
      *(float4*)(&ms[s][o*4]) = *(const float4*)(memf + (size_t)sidx[h*8+s]*C_DIM + o*4);
    }
    __syncthreads();
    for (int v=0; v<16; ++v){
      int m = blockIdx.x*64 + wid*16 + v;
      const float* row = memf + (size_t)m*C_DIM;
      float rf[24];
      #pragma unroll
      for (int i=0;i<6;++i){
        float4 rv = *(const float4*)(row + i*256 + lane*4);
        rf[i*4+0]=rv.x; rf[i*4+1]=rv.y; rf[i*4+2]=rv.z; rf[i*4+3]=rv.w;
      }
      float mnv = mn[m];
      for (int s=0;s<8;++s){
        float acc=0.f;
        #pragma unroll
        for (int i=0;i<6;++i){
          float4 w = *(const float4*)(&ms[s][i*256 + lane*4]);
          acc += rf[i*4+0]*w.x + rf[i*4+1]*w.y + rf[i*4+2]*w.z + rf[i*4+3]*w.w;
        }
        #pragma unroll
        for (int msk=32;msk;msk>>=1) acc += __shfl_xor(acc, msk);
        if (lane==0)
          dmat[(size_t)(h*8+s)*M_MEM + m] = sqrtf(fmaxf(snrm[h*8+s] + mnv - 2.0f*acc, 0.f));
      }
    }
  }
}

// ---------------------------------------------------------------------------
// 8) per-batch top-10 smallest distances -> reweighted score (parallel merge)
// ---------------------------------------------------------------------------
__device__ __forceinline__ void top10_scan(const float* src, int n, float* tp){
  #pragma unroll
  for (int i=0;i<10;++i) tp[i]=FINF;
  for (int c=0;c<n;++c){
    float v=src[c];
    if (v < tp[9]){
      #pragma unroll
      for (int j=0;j<10;++j){ float lo=fminf(tp[j],v); v=fmaxf(tp[j],v); tp[j]=lo; }
    }
  }
}

__global__ __launch_bounds__(256) void score_k(const float* __restrict__ dmat,
                                               const float* __restrict__ sstar,
                                               float* __restrict__ out){
  int b=blockIdx.x, t=threadIdx.x;
  float top[10];
  #pragma unroll
  for (int i=0;i<10;++i) top[i]=FINF;
  for (int i=0;i<64;++i){
    float v = dmat[(size_t)b*M_MEM + i*256 + t];
    if (v < top[9]){
      #pragma unroll
      for (int j=0;j<10;++j){ float lo=fminf(top[j],v); v=fmaxf(top[j],v); top[j]=lo; }
    }
  }
  __shared__ float cand[2560];
  __shared__ float l1[640];
  __shared__ float l2[160];
  __shared__ float l3[40];
  #pragma unroll
  for (int i=0;i<10;++i) cand[t*10+i]=top[i];
  __syncthreads();
  if (t < 64){
    float tp[10]; top10_scan(&cand[t*40], 40, tp);
    #pragma unroll
    for (int i=0;i<10;++i) l1[t*10+i]=tp[i];
  }
  __syncthreads();
  if (t < 16){
    float tp[10]; top10_scan(&l1[t*40], 40, tp);
    #pragma unroll
    for (int i=0;i<10;++i) l2[t*10+i]=tp[i];
  }
  __syncthreads();
  if (t < 4){
    float tp[10]; top10_scan(&l2[t*40], 40, tp);
    #pragma unroll
    for (int i=0;i<10;++i) l3[t*10+i]=tp[i];
  }
  __syncthreads();
  if (t==0){
    float tp[10]; top10_scan(l3, 40, tp);
    // drop tp[0] (self); w = 1 - exp(d1)/sum = 1 - 1/sum(exp(di-d1))
    float d1 = tp[1];
    float ssum = 0.f;
    #pragma unroll
    for (int i=1;i<10;++i) ssum += expf(tp[i]-d1);
    out[b] = (1.0f - 1.0f/ssum) * sstar[b];
  }
}

// ---------------------------------------------------------------------------
extern "C" void kernel_launch(void* const* d_in, const int* in_sizes, int n_in,
                              void* d_out, int out_size, void* d_ws, size_t ws_size,
                              hipStream_t stream){
  const float* feat = (const float*)d_in[0];
  const float* memf = (const float*)d_in[1];
  float* out = (float*)d_out;
  char* ws = (char*)d_ws;

  size_t o_fb = 0;
  size_t o_mb = o_fb + (size_t)N_FEAT*C_DIM;          // fp8
  size_t o_fn = o_mb + (size_t)M_MEM*C_DIM;           // fp8
  size_t o_mn = o_fn + (size_t)N_FEAT*4;
  size_t o_p1 = o_mn + (size_t)M_MEM*4;
  size_t o_x1 = o_p1 + (size_t)N_FEAT*NMT*4;
  size_t o_p2 = o_x1 + (size_t)N_FEAT*NMT*4;
  size_t o_x2 = o_p2 + (size_t)N_FEAT*NMT*4;
  size_t o_nd = o_x2 + (size_t)N_FEAT*NMT*4;
  size_t o_ni = o_nd + (size_t)N_FEAT*4;
  size_t o_wt = o_ni + (size_t)N_FEAT*4;
  size_t o_ss = o_wt + (size_t)16*256*4;
  size_t o_mi = o_ss + (size_t)NBATCH*4;
  size_t o_dm = o_mi + (size_t)NBATCH*4;
  size_t need = o_dm + (size_t)NBATCH*M_MEM*4;
  if (ws_size < need) return;

  u8*    fb  = (u8*)(ws+o_fb);
  u8*    mb  = (u8*)(ws+o_mb);
  float* fn  = (float*)(ws+o_fn);
  float* mn  = (float*)(ws+o_mn);
  float* p1  = (float*)(ws+o_p1);
  int*   x1  = (int*)(ws+o_x1);
  float* p2  = (float*)(ws+o_p2);
  int*   x2  = (int*)(ws+o_x2);
  float* nd  = (float*)(ws+o_nd);
  int*   ni  = (int*)(ws+o_ni);
  float* wt  = (float*)(ws+o_wt);
  float* ss  = (float*)(ws+o_ss);
  int*   mi  = (int*)(ws+o_mi);
  float* dm  = (float*)(ws+o_dm);

  conv_norm_k<<<N_FEAT/4, 256, 0, stream>>>(feat, fb, fn);
  conv_norm_k<<<M_MEM/4, 256, 0, stream>>>(memf, mb, mn);
  dist_fp8_k<<<8192, 256, 0, stream>>>(fb, mb, fn, mn, p1, x1, p2, x2);
  refine_k<<<N_FEAT/4, 256, 0, stream>>>(feat, memf, fn, mn, p1, x1, p2, x2, nd, ni);
  build_WT<<<1, 256, 0, stream>>>(wt);
  argmax_k<<<NBATCH, 256, 0, stream>>>(nd, ni, ss, mi);
  mdist_k<<<M_MEM/64, 256, 0, stream>>>(memf, mn, mi, dm);
  amap_k<<<dim3(NBATCH, 8), 256, 0, stream>>>(nd, wt, out + 32);
  score_k<<<NBATCH, 256, 0, stream>>>(dm, ss, out);
}

// Round 9
// 866.621 us; speedup vs baseline: 2.8992x; 2.8992x over previous
//
#include <hip/hip_runtime.h>

typedef unsigned short u16;
typedef __bf16 bf16x8 __attribute__((ext_vector_type(8)));
typedef float f32x4 __attribute__((ext_vector_type(4)));
typedef u16 u16x8 __attribute__((ext_vector_type(8)));
typedef u16 u16x4 __attribute__((ext_vector_type(4)));

#define N_FEAT 8192
#define M_MEM 16384
#define C_DIM 1536
#define NBATCH 32
#define NKT 24            // 1536/64 K-tiles (BK=64)
#define NMT 128           // 16384/128 memory tiles (two per 256-col block)
#define FINF 3.4e38f

__device__ __forceinline__ u16 f2bf(float x){           // RTNE fp32->bf16
  unsigned u = __float_as_uint(x);
  u += 0x7fffu + ((u >> 16) & 1u);
  return (u16)(u >> 16);
}
__device__ __forceinline__ float bf2f(u16 h){
  return __uint_as_float(((unsigned)h) << 16);
}

#define GLDS16(g, l) __builtin_amdgcn_global_load_lds( \
    (const __attribute__((address_space(1))) void*)(g), \
    (__attribute__((address_space(3))) void*)(l), 16, 0, 0)

// ---------------------------------------------------------------------------
// 1) fp32 -> bf16 copy + exact fp32 row norms. 1 wave per row, 4 rows/block.
// ---------------------------------------------------------------------------
__global__ __launch_bounds__(256) void conv_norm_k(const float* __restrict__ in,
                                                   u16* __restrict__ ob,
                                                   float* __restrict__ nrm){
  int row  = blockIdx.x*4 + (threadIdx.x>>6);
  int lane = threadIdx.x & 63;
  const float* r = in + (size_t)row*C_DIM;
  u16* o = ob + (size_t)row*C_DIM;
  float s = 0.f;
  #pragma unroll
  for (int i=0;i<6;++i){
    int idx = i*256 + lane*4;
    float4 v = *(const float4*)(r + idx);
    s += v.x*v.x + v.y*v.y + v.z*v.z + v.w*v.w;
    u16x4 u; u.x=f2bf(v.x); u.y=f2bf(v.y); u.z=f2bf(v.z); u.w=f2bf(v.w);
    *(u16x4*)(o + idx) = u;
  }
  #pragma unroll
  for (int m=32;m;m>>=1) s += __shfl_xor(s, m);
  if (lane==0) nrm[row] = s;
}

// ---------------------------------------------------------------------------
// 2) 256x256 bf16 MFMA distance (best-measured schedule: 4-phase lockstep,
//    counted vmcnt, rect XCD remap) + fused min/argmin emitted at 128-col
//    granularity (2 outputs per block) to feed the cheap 128-tile refine.
// ---------------------------------------------------------------------------
__global__ __launch_bounds__(512, 2) void dist256_k(const u16* __restrict__ fb,
                                                    const u16* __restrict__ mb,
                                                    const float* __restrict__ fn,
                                                    const float* __restrict__ mn,
                                                    float* __restrict__ pmin,
                                                    int* __restrict__ pidx){
  __shared__ u16 lds[65536];          // 128 KiB: 2 bufs x (A 32K + B 32K)
  const int tid = threadIdx.x;
  const int bid = blockIdx.x;
  // XCD-aware 2D remap: co-resident 32 blocks/XCD = 4 nt x 8 mt rectangle.
  const int xcd = bid & 7;
  const int li  = bid >> 3;                     // 0..255 within XCD
  const int nt  = ((li >> 5) << 2) | (li & 3);  // 0..31 feature tile
  const int mt  = (xcd << 3) | ((li >> 2) & 7); // 0..63 memory tile (256-col)
  const int wid = tid >> 6, lane = tid & 63;
  const int wm = wid >> 2, wn = wid & 3;        // 2x4 waves, each 128x64 out
  const int lr = lane & 15, lk = lane >> 4;
  const int slk8 = (lk ^ ((lr >> 1) & 3)) * 8;  // swizzled read chunk (u16 units)
  const int sgc  = (tid & 3) ^ ((tid >> 3) & 3);// pre-swizzled source chunk
  const int arow0 = nt*256, brow0 = mt*256;

  // u16-unit LDS offsets: buf stride 32768, B at +16384, kk at +8192, h at +4096
#define ISSUE_A(kt, kk, h, bb) GLDS16( \
    fb + (size_t)(arow0 + (h)*128 + (tid>>2))*C_DIM + (kt)*64 + (kk)*32 + sgc*8, \
    lds + (bb)*32768 + (kk)*8192 + (h)*4096 + tid*8)
#define ISSUE_B(kt, kk, h, bb) GLDS16( \
    mb + (size_t)(brow0 + (h)*128 + (tid>>2))*C_DIM + (kt)*64 + (kk)*32 + sgc*8, \
    lds + (bb)*32768 + 16384 + (kk)*8192 + (h)*4096 + tid*8)
#define LDA(bo, kk, row) (*(const bf16x8*)(lds + (bo) + (kk)*8192 + (row)*32 + slk8))
#define LDB(bo, kk, row) (*(const bf16x8*)(lds + (bo) + 16384 + (kk)*8192 + (row)*32 + slk8))
#define BAR()   __builtin_amdgcn_s_barrier()
#define LGKM0() asm volatile("s_waitcnt lgkmcnt(0)" ::: "memory")

  f32x4 acc[8][4];
  #pragma unroll
  for (int m=0;m<8;++m)
    #pragma unroll
    for (int n=0;n<4;++n) acc[m][n] = (f32x4){0.f,0.f,0.f,0.f};

  // prologue: K-tile 0 (8 issues) + K-tile 1 kk0 (4 issues); wait K-tile 0.
  ISSUE_A(0,0,0,0); ISSUE_A(0,0,1,0); ISSUE_B(0,0,0,0); ISSUE_B(0,0,1,0);
  ISSUE_A(0,1,0,0); ISSUE_A(0,1,1,0); ISSUE_B(0,1,0,0); ISSUE_B(0,1,1,0);
  ISSUE_A(1,0,0,1); ISSUE_A(1,0,1,1); ISSUE_B(1,0,0,1); ISSUE_B(1,0,1,1);
  asm volatile("s_waitcnt vmcnt(4)" ::: "memory");
  BAR();

  for (int u=0; u<NKT; ++u){
    const int b  = u & 1, nb = b ^ 1;
    const int bo = b*32768;
    const int kt1 = (u+1 < NKT) ? u+1 : NKT-1;
    const int kt2 = (u+2 < NKT) ? u+2 : NKT-1;
    bf16x8 av[4], bv[4];

    // ---- ph1: kk0, m 0-3 ---------------------------------------------
    #pragma unroll
    for (int n=0;n<4;++n) bv[n] = LDB(bo, 0, wn*64 + n*16 + lr);
    #pragma unroll
    for (int m=0;m<4;++m) av[m] = LDA(bo, 0, wm*128 + m*16 + lr);
    ISSUE_A(kt1,1,0,nb); ISSUE_A(kt1,1,1,nb);
    BAR(); LGKM0();
    __builtin_amdgcn_s_setprio(1);
    #pragma unroll
    for (int m=0;m<4;++m)
      #pragma unroll
      for (int n=0;n<4;++n)
        acc[m][n] = __builtin_amdgcn_mfma_f32_16x16x32_bf16(av[m], bv[n], acc[m][n],0,0,0);
    __builtin_amdgcn_s_setprio(0);
    BAR();

    // ---- ph2: kk0, m 4-7 (bv reused) ---------------------------------
    #pragma unroll
    for (int m=0;m<4;++m) av[m] = LDA(bo, 0, wm*128 + 64 + m*16 + lr);
    ISSUE_B(kt1,1,0,nb); ISSUE_B(kt1,1,1,nb);
    BAR(); LGKM0();
    __builtin_amdgcn_s_setprio(1);
    #pragma unroll
    for (int m=0;m<4;++m)
      #pragma unroll
      for (int n=0;n<4;++n)
        acc[4+m][n] = __builtin_amdgcn_mfma_f32_16x16x32_bf16(av[m], bv[n], acc[4+m][n],0,0,0);
    __builtin_amdgcn_s_setprio(0);
    BAR();

    // ---- ph3: kk1, m 0-3 ---------------------------------------------
    #pragma unroll
    for (int n=0;n<4;++n) bv[n] = LDB(bo, 1, wn*64 + n*16 + lr);
    #pragma unroll
    for (int m=0;m<4;++m) av[m] = LDA(bo, 1, wm*128 + m*16 + lr);
    ISSUE_A(kt2,0,0,b); ISSUE_A(kt2,0,1,b);   // A@kk0 of buf b free after ph2
    BAR(); LGKM0();
    __builtin_amdgcn_s_setprio(1);
    #pragma unroll
    for (int m=0;m<4;++m)
      #pragma unroll
      for (int n=0;n<4;++n)
        acc[m][n] = __builtin_amdgcn_mfma_f32_16x16x32_bf16(av[m], bv[n], acc[m][n],0,0,0);
    __builtin_amdgcn_s_setprio(0);
    BAR();

    // ---- ph4: kk1, m 4-7 ---------------------------------------------
    #pragma unroll
    for (int m=0;m<4;++m) av[m] = LDA(bo, 1, wm*128 + 64 + m*16 + lr);
    ISSUE_B(kt2,0,0,b); ISSUE_B(kt2,0,1,b);   // B@kk0 of buf b free after ph1
    BAR(); LGKM0();
    __builtin_amdgcn_s_setprio(1);
    #pragma unroll
    for (int m=0;m<4;++m)
      #pragma unroll
      for (int n=0;n<4;++n)
        acc[4+m][n] = __builtin_amdgcn_mfma_f32_16x16x32_bf16(av[m], bv[n], acc[4+m][n],0,0,0);
    __builtin_amdgcn_s_setprio(0);
    asm volatile("s_waitcnt vmcnt(4)" ::: "memory");  // next K-tile fully landed
    BAR();
  }

  asm volatile("s_waitcnt vmcnt(0)" ::: "memory");    // drain tail prefetches
  __syncthreads();                                    // before LDS reuse

  // epilogue: d = sqrt(max(fa + mb - 2ab, 0)); min/argmin per 128-col half.
  // C/D frag layout: col = lane&15, row = (lane>>4)*4 + reg
  const int rowbase = nt*256 + wm*128;
  const int colbase = mt*256 + wn*64;
  float mnv[4];
  #pragma unroll
  for (int n=0;n<4;++n) mnv[n] = mn[colbase + n*16 + lr];
  float* smf = (float*)lds;               // [4][256]
  int*   sii = (int*)((char*)lds + 4096); // [4][256]
  #pragma unroll
  for (int m=0;m<8;++m){
    float mv[4]; int mi[4];
    #pragma unroll
    for (int r=0;r<4;++r){
      float fa = fn[rowbase + m*16 + lk*4 + r];
      mv[r] = FINF; mi[r] = 0x7fffffff;
      #pragma unroll
      for (int n=0;n<4;++n){
        int ci = colbase + n*16 + lr;
        float d2 = fa + mnv[n] - 2.0f*acc[m][n][r];
        float d = sqrtf(fmaxf(d2, 0.0f));
        if (d < mv[r]){ mv[r] = d; mi[r] = ci; }
      }
    }
    #pragma unroll
    for (int msk=1; msk<16; msk<<=1){
      #pragma unroll
      for (int r=0;r<4;++r){
        float ov = __shfl_xor(mv[r], msk);
        int   oi = __shfl_xor(mi[r], msk);
        if (ov < mv[r] || (ov == mv[r] && oi < mi[r])){ mv[r]=ov; mi[r]=oi; }
      }
    }
    if (lr == 0){
      #pragma unroll
      for (int r=0;r<4;++r){
        int rl = wm*128 + m*16 + lk*4 + r;
        smf[wn*256 + rl] = mv[r];
        sii[wn*256 + rl] = mi[r];
      }
    }
  }
  __syncthreads();
  if (tid < 256){
    // halves {wn 0,1} -> 128-col tile 2mt ; {wn 2,3} -> 2mt+1
    float va = smf[tid];       int ia = sii[tid];
    float v1 = smf[256+tid];   int i1 = sii[256+tid];
    if (v1 < va || (v1==va && i1<ia)){ va=v1; ia=i1; }
    float vb = smf[512+tid];   int ib = sii[512+tid];
    float v3 = smf[768+tid];   int i3 = sii[768+tid];
    if (v3 < vb || (v3==vb && i3<ib)){ vb=v3; ib=i3; }
    size_t o = (size_t)(nt*256 + tid)*NMT;
    pmin[o + 2*mt]   = va; pidx[o + 2*mt]   = ia;
    pmin[o + 2*mt+1] = vb; pidx[o + 2*mt+1] = ib;
  }
#undef ISSUE_A
#undef ISSUE_B
#undef LDA
#undef LDB
#undef BAR
#undef LGKM0
}

// ---------------------------------------------------------------------------
// 3) refine: exact fp32 distance for candidates within band of bf16 min
//    -> exact nn_dists / nn_indices (selection-exact vs reference).
// ---------------------------------------------------------------------------
__global__ __launch_bounds__(256) void refine_k(const float* __restrict__ feat,
                                                const float* __restrict__ memf,
                                                const float* __restrict__ fn,
                                                const float* __restrict__ mn,
                                                const float* __restrict__ pmin,
                                                const int* __restrict__ pidx,
                                                float* __restrict__ nnd,
                                                int* __restrict__ nni){
  int wid = threadIdx.x>>6, lane = threadIdx.x&63;
  int row = blockIdx.x*4 + wid;
  const float* pm = pmin + (size_t)row*NMT;
  const int*   pi = pidx + (size_t)row*NMT;
  float v0 = pm[lane], v1 = pm[64+lane];
  float mv = fminf(v0, v1);
  #pragma unroll
  for (int m=32;m;m>>=1) mv = fminf(mv, __shfl_xor(mv, m));
  float band = mv + 0.02f;   // covers bf16-GEMM error (~16 sigma)
  unsigned long long b0 = __ballot(v0 <= band);
  unsigned long long b1 = __ballot(v1 <= band);

  float fr[24];
  const float* f = feat + (size_t)row*C_DIM;
  #pragma unroll
  for (int i=0;i<6;++i){
    float4 t = *(const float4*)(f + i*256 + lane*4);
    fr[i*4+0]=t.x; fr[i*4+1]=t.y; fr[i*4+2]=t.z; fr[i*4+3]=t.w;
  }
  float fa = fn[row];
  float bd = FINF; int bi = 0x7fffffff;
  while (b0 | b1){
    int t;
    if (b0){ t = __ffsll(b0)-1; b0 &= b0-1; }
    else   { t = 64 + __ffsll(b1)-1; b1 &= b1-1; }
    int cidx = pi[t];
    const float* mrow = memf + (size_t)cidx*C_DIM;
    float acc = 0.f;
    #pragma unroll
    for (int i=0;i<6;++i){
      float4 m4 = *(const float4*)(mrow + i*256 + lane*4);
      acc += fr[i*4+0]*m4.x + fr[i*4+1]*m4.y + fr[i*4+2]*m4.z + fr[i*4+3]*m4.w;
    }
    #pragma unroll
    for (int m=32;m;m>>=1) acc += __shfl_xor(acc, m);
    float d = sqrtf(fmaxf(fa + mn[cidx] - 2.0f*acc, 0.f));
    if (d < bd || (d == bd && cidx < bi)){ bd = d; bi = cidx; }
  }
  if (lane==0){ nnd[row]=bd; nni[row]=bi; }
}

// ---------------------------------------------------------------------------
// 4) WT[i][y] = composite (gaussian-zero-pad o bilinear-halfpixel) weights
// ---------------------------------------------------------------------------
__global__ void build_WT(float* __restrict__ WT){
  int y = threadIdx.x;                 // 256 threads, 1 block
  float g[25]; float Z = 0.f;
  #pragma unroll
  for (int k=0;k<25;++k){ float x=(float)(k-12)*0.25f; g[k]=expf(-0.5f*x*x); Z+=g[k]; }
  float acc[16];
  #pragma unroll
  for (int i=0;i<16;++i) acc[i]=0.f;
  for (int dy=0; dy<25; ++dy){
    int yy = y - 12 + dy;
    if (yy < 0 || yy > 255) continue;
    float gg = g[dy]/Z;
    float src = ((float)yy + 0.5f)*0.0625f - 0.5f;
    int i0 = (int)floorf(src);
    float fz = src - (float)i0;
    if (i0 < 0){ i0 = 0; fz = 0.f; }
    else if (i0 >= 15){ i0 = 15; fz = 0.f; }
    acc[i0] += gg*(1.f-fz);
    if (fz > 0.f) acc[i0+1] += gg*fz;
  }
  for (int i=0;i<16;++i) WT[i*256 + y] = acc[i];
}

// ---------------------------------------------------------------------------
// 5) amap[b] = W ps[b] W^T  (separable; exact fp32)
// ---------------------------------------------------------------------------
__global__ __launch_bounds__(256) void amap_k(const float* __restrict__ nnd,
                                              const float* __restrict__ WT,
                                              float* __restrict__ out){
  __shared__ float ps[256];
  __shared__ float wt[16*256];
  __shared__ float tmp[16*256];
  int b = blockIdx.x, yc = blockIdx.y, t = threadIdx.x;
  ps[t] = nnd[b*256 + t];
  #pragma unroll
  for (int i=0;i<16;++i) wt[i*256+t] = WT[i*256+t];
  __syncthreads();
  #pragma unroll
  for (int i=0;i<16;++i){
    float s=0.f;
    #pragma unroll
    for (int j=0;j<16;++j) s += wt[j*256+t]*ps[i*16+j];
    tmp[i*256+t]=s;
  }
  __syncthreads();
  float* ob = out + ((size_t)b<<16) + yc*32*256 + t;
  for (int yy=0; yy<32; ++yy){
    int y = yc*32+yy;
    float s=0.f;
    #pragma unroll
    for (int i=0;i<16;++i) s += wt[i*256+y]*tmp[i*256+t];
    ob[(size_t)yy*256] = s;
  }
}

// ---------------------------------------------------------------------------
// 6) per-batch argmax of patch scores -> s_star, m_star_idx
// ---------------------------------------------------------------------------
__global__ void argmax_k(const float* __restrict__ nnd, const int* __restrict__ nni,
                         float* __restrict__ sstar, int* __restrict__ midx){
  int b=blockIdx.x, t=threadIdx.x, lane=t&63, wid=t>>6;
  float v = nnd[b*256+t]; int i=t;
  #pragma unroll
  for (int m=1;m<64;m<<=1){
    float ov=__shfl_xor(v,m); int oi=__shfl_xor(i,m);
    if (ov > v || (ov==v && oi<i)){ v=ov; i=oi; }
  }
  __shared__ float sv[4]; __shared__ int si[4];
  if (lane==0){ sv[wid]=v; si[wid]=i; }
  __syncthreads();
  if (t==0){
    for (int w=1;w<4;++w){ if (sv[w]>v || (sv[w]==v && si[w]<i)){ v=sv[w]; i=si[w]; } }
    sstar[b]=v; midx[b]=nni[b*256+i];
  }
}

// ---------------------------------------------------------------------------
// 7) m_dists: 32 m_star vectors (bf16, half staged in LDS) vs all memory rows
// ---------------------------------------------------------------------------
__global__ __launch_bounds__(256) void mdist_k(const u16* __restrict__ mb,
                                               const float* __restrict__ mn,
                                               const int* __restrict__ midx,
                                               float* __restrict__ dmat){
  __shared__ u16 ms[16*C_DIM];       // 48 KiB: stage 16 m_stars per half
  __shared__ int sidx[32]; __shared__ float snrm[32];
  int t = threadIdx.x;
  if (t < 32){ int r = midx[t]; sidx[t]=r; snrm[t]=mn[r]; }
  int wid=t>>6, lane=t&63;
  for (int h=0; h<2; ++h){
    __syncthreads();
    for (int c=t; c<3072; c+=256){     // 16 rows x 192 x 16B chunks
      int s = c/192, o = c - s*192;
      *(u16x8*)(&ms[s*C_DIM + o*8]) = *(const u16x8*)(mb + (size_t)sidx[h*16+s]*C_DIM + o*8);
    }
    __syncthreads();
    for (int v=0; v<16; ++v){
      int m = blockIdx.x*64 + wid*16 + v;
      const u16* row = mb + (size_t)m*C_DIM;
      float rf[24];
      #pragma unroll
      for (int i=0;i<3;++i){
        u16x8 rv = *(const u16x8*)(row + i*512 + lane*8);
        #pragma unroll
        for (int j=0;j<8;++j) rf[i*8+j] = bf2f(rv[j]);
      }
      float mnv = mn[m];
      for (int s=0;s<16;++s){
        float acc=0.f;
        #pragma unroll
        for (int i=0;i<3;++i){
          u16x8 w = *(const u16x8*)(&ms[s*C_DIM + i*512 + lane*8]);
          #pragma unroll
          for (int j=0;j<8;++j) acc += rf[i*8+j]*bf2f(w[j]);
        }
        #pragma unroll
        for (int msk=32;msk;msk>>=1) acc += __shfl_xor(acc, msk);
        if (lane==0)
          dmat[(size_t)(h*16+s)*M_MEM + m] = sqrtf(fmaxf(snrm[h*16+s] + mnv - 2.0f*acc, 0.f));
      }
    }
  }
}

// ---------------------------------------------------------------------------
// 8) per-batch top-10 smallest distances -> reweighted score (parallel merge)
// ---------------------------------------------------------------------------
__device__ __forceinline__ void top10_scan(const float* src, int n, float* tp){
  #pragma unroll
  for (int i=0;i<10;++i) tp[i]=FINF;
  for (int c=0;c<n;++c){
    float v=src[c];
    if (v < tp[9]){
      #pragma unroll
      for (int j=0;j<10;++j){ float lo=fminf(tp[j],v); v=fmaxf(tp[j],v); tp[j]=lo; }
    }
  }
}

__global__ __launch_bounds__(256) void score_k(const float* __restrict__ dmat,
                                               const float* __restrict__ sstar,
                                               float* __restrict__ out){
  int b=blockIdx.x, t=threadIdx.x;
  float top[10];
  #pragma unroll
  for (int i=0;i<10;++i) top[i]=FINF;
  for (int i=0;i<64;++i){
    float v = dmat[(size_t)b*M_MEM + i*256 + t];
    if (v < top[9]){
      #pragma unroll
      for (int j=0;j<10;++j){ float lo=fminf(top[j],v); v=fmaxf(top[j],v); top[j]=lo; }
    }
  }
  __shared__ float cand[2560];
  __shared__ float l1[640];
  __shared__ float l2[160];
  __shared__ float l3[40];
  #pragma unroll
  for (int i=0;i<10;++i) cand[t*10+i]=top[i];
  __syncthreads();
  if (t < 64){
    float tp[10]; top10_scan(&cand[t*40], 40, tp);
    #pragma unroll
    for (int i=0;i<10;++i) l1[t*10+i]=tp[i];
  }
  __syncthreads();
  if (t < 16){
    float tp[10]; top10_scan(&l1[t*40], 40, tp);
    #pragma unroll
    for (int i=0;i<10;++i) l2[t*10+i]=tp[i];
  }
  __syncthreads();
  if (t < 4){
    float tp[10]; top10_scan(&l2[t*40], 40, tp);
    #pragma unroll
    for (int i=0;i<10;++i) l3[t*10+i]=tp[i];
  }
  __syncthreads();
  if (t==0){
    float tp[10]; top10_scan(l3, 40, tp);
    // drop tp[0] (self); w = 1 - exp(d1)/sum = 1 - 1/sum(exp(di-d1))
    float d1 = tp[1];
    float ssum = 0.f;
    #pragma unroll
    for (int i=1;i<10;++i) ssum += expf(tp[i]-d1);
    out[b] = (1.0f - 1.0f/ssum) * sstar[b];
  }
}

// ---------------------------------------------------------------------------
extern "C" void kernel_launch(void* const* d_in, const int* in_sizes, int n_in,
                              void* d_out, int out_size, void* d_ws, size_t ws_size,
                              hipStream_t stream){
  const float* feat = (const float*)d_in[0];
  const float* memf = (const float*)d_in[1];
  float* out = (float*)d_out;
  char* ws = (char*)d_ws;

  size_t o_fb = 0;
  size_t o_mb = o_fb + (size_t)N_FEAT*C_DIM*2;
  size_t o_fn = o_mb + (size_t)M_MEM*C_DIM*2;
  size_t o_mn = o_fn + (size_t)N_FEAT*4;
  size_t o_pv = o_mn + (size_t)M_MEM*4;
  size_t o_pi = o_pv + (size_t)N_FEAT*NMT*4;
  size_t o_nd = o_pi + (size_t)N_FEAT*NMT*4;
  size_t o_ni = o_nd + (size_t)N_FEAT*4;
  size_t o_wt = o_ni + (size_t)N_FEAT*4;
  size_t o_ss = o_wt + (size_t)16*256*4;
  size_t o_mi = o_ss + (size_t)NBATCH*4;
  size_t o_dm = o_mi + (size_t)NBATCH*4;
  size_t need = o_dm + (size_t)NBATCH*M_MEM*4;
  if (ws_size < need) return;

  u16*   fb  = (u16*)(ws+o_fb);
  u16*   mb  = (u16*)(ws+o_mb);
  float* fn  = (float*)(ws+o_fn);
  float* mn  = (float*)(ws+o_mn);
  float* pv  = (float*)(ws+o_pv);
  int*   pi  = (int*)(ws+o_pi);
  float* nd  = (float*)(ws+o_nd);
  int*   ni  = (int*)(ws+o_ni);
  float* wt  = (float*)(ws+o_wt);
  float* ss  = (float*)(ws+o_ss);
  int*   mi  = (int*)(ws+o_mi);
  float* dm  = (float*)(ws+o_dm);

  conv_norm_k<<<N_FEAT/4, 256, 0, stream>>>(feat, fb, fn);
  conv_norm_k<<<M_MEM/4, 256, 0, stream>>>(memf, mb, mn);
  dist256_k<<<2048, 512, 0, stream>>>(fb, mb, fn, mn, pv, pi);
  refine_k<<<N_FEAT/4, 256, 0, stream>>>(feat, memf, fn, mn, pv, pi, nd, ni);
  build_WT<<<1, 256, 0, stream>>>(wt);
  argmax_k<<<NBATCH, 256, 0, stream>>>(nd, ni, ss, mi);
  mdist_k<<<M_MEM/64, 256, 0, stream>>>(mb, mn, mi, dm);
  amap_k<<<dim3(NBATCH, 8), 256, 0, stream>>>(nd, wt, out + 32);
  score_k<<<NBATCH, 256, 0, stream>>>(dm, ss, out);
}

// Round 10
// 776.839 us; speedup vs baseline: 3.2343x; 1.1156x over previous
//
#include <hip/hip_runtime.h>

typedef unsigned short u16;
typedef __bf16 bf16x8 __attribute__((ext_vector_type(8)));
typedef float f32x4 __attribute__((ext_vector_type(4)));
typedef u16 u16x8 __attribute__((ext_vector_type(8)));
typedef u16 u16x4 __attribute__((ext_vector_type(4)));

#define N_FEAT 8192
#define M_MEM 16384
#define C_DIM 1536
#define NBATCH 32
#define NKT 24            // 1536/64 K-tiles (BK=64)
#define NMT 128           // 16384/128 memory tiles (two per 256-col block)
#define FINF 3.4e38f

__device__ __forceinline__ u16 f2bf(float x){           // RTNE fp32->bf16
  unsigned u = __float_as_uint(x);
  u += 0x7fffu + ((u >> 16) & 1u);
  return (u16)(u >> 16);
}
__device__ __forceinline__ float bf2f(u16 h){
  return __uint_as_float(((unsigned)h) << 16);
}

#define GLDS16(g, l) __builtin_amdgcn_global_load_lds( \
    (const __attribute__((address_space(1))) void*)(g), \
    (__attribute__((address_space(3))) void*)(l), 16, 0, 0)

// ---------------------------------------------------------------------------
// 1) fp32 -> bf16 copy + exact fp32 row norms. 1 wave per row, 4 rows/block.
// ---------------------------------------------------------------------------
__global__ __launch_bounds__(256) void conv_norm_k(const float* __restrict__ in,
                                                   u16* __restrict__ ob,
                                                   float* __restrict__ nrm){
  int row  = blockIdx.x*4 + (threadIdx.x>>6);
  int lane = threadIdx.x & 63;
  const float* r = in + (size_t)row*C_DIM;
  u16* o = ob + (size_t)row*C_DIM;
  float s = 0.f;
  #pragma unroll
  for (int i=0;i<6;++i){
    int idx = i*256 + lane*4;
    float4 v = *(const float4*)(r + idx);
    s += v.x*v.x + v.y*v.y + v.z*v.z + v.w*v.w;
    u16x4 u; u.x=f2bf(v.x); u.y=f2bf(v.y); u.z=f2bf(v.z); u.w=f2bf(v.w);
    *(u16x4*)(o + idx) = u;
  }
  #pragma unroll
  for (int m=32;m;m>>=1) s += __shfl_xor(s, m);
  if (lane==0) nrm[row] = s;
}

// ---------------------------------------------------------------------------
// 2) 256x256 bf16 MFMA distance (best-measured schedule: 4-phase lockstep,
//    counted vmcnt, rect XCD remap) + fused min/argmin emitted at 128-col
//    granularity (2 outputs per block). UNCHANGED from round 9 (control).
// ---------------------------------------------------------------------------
__global__ __launch_bounds__(512, 2) void dist256_k(const u16* __restrict__ fb,
                                                    const u16* __restrict__ mb,
                                                    const float* __restrict__ fn,
                                                    const float* __restrict__ mn,
                                                    float* __restrict__ pmin,
                                                    int* __restrict__ pidx){
  __shared__ u16 lds[65536];          // 128 KiB: 2 bufs x (A 32K + B 32K)
  const int tid = threadIdx.x;
  const int bid = blockIdx.x;
  // XCD-aware 2D remap: co-resident 32 blocks/XCD = 4 nt x 8 mt rectangle.
  const int xcd = bid & 7;
  const int li  = bid >> 3;                     // 0..255 within XCD
  const int nt  = ((li >> 5) << 2) | (li & 3);  // 0..31 feature tile
  const int mt  = (xcd << 3) | ((li >> 2) & 7); // 0..63 memory tile (256-col)
  const int wid = tid >> 6, lane = tid & 63;
  const int wm = wid >> 2, wn = wid & 3;        // 2x4 waves, each 128x64 out
  const int lr = lane & 15, lk = lane >> 4;
  const int slk8 = (lk ^ ((lr >> 1) & 3)) * 8;  // swizzled read chunk (u16 units)
  const int sgc  = (tid & 3) ^ ((tid >> 3) & 3);// pre-swizzled source chunk
  const int arow0 = nt*256, brow0 = mt*256;

  // u16-unit LDS offsets: buf stride 32768, B at +16384, kk at +8192, h at +4096
#define ISSUE_A(kt, kk, h, bb) GLDS16( \
    fb + (size_t)(arow0 + (h)*128 + (tid>>2))*C_DIM + (kt)*64 + (kk)*32 + sgc*8, \
    lds + (bb)*32768 + (kk)*8192 + (h)*4096 + tid*8)
#define ISSUE_B(kt, kk, h, bb) GLDS16( \
    mb + (size_t)(brow0 + (h)*128 + (tid>>2))*C_DIM + (kt)*64 + (kk)*32 + sgc*8, \
    lds + (bb)*32768 + 16384 + (kk)*8192 + (h)*4096 + tid*8)
#define LDA(bo, kk, row) (*(const bf16x8*)(lds + (bo) + (kk)*8192 + (row)*32 + slk8))
#define LDB(bo, kk, row) (*(const bf16x8*)(lds + (bo) + 16384 + (kk)*8192 + (row)*32 + slk8))
#define BAR()   __builtin_amdgcn_s_barrier()
#define LGKM0() asm volatile("s_waitcnt lgkmcnt(0)" ::: "memory")

  f32x4 acc[8][4];
  #pragma unroll
  for (int m=0;m<8;++m)
    #pragma unroll
    for (int n=0;n<4;++n) acc[m][n] = (f32x4){0.f,0.f,0.f,0.f};

  // prologue: K-tile 0 (8 issues) + K-tile 1 kk0 (4 issues); wait K-tile 0.
  ISSUE_A(0,0,0,0); ISSUE_A(0,0,1,0); ISSUE_B(0,0,0,0); ISSUE_B(0,0,1,0);
  ISSUE_A(0,1,0,0); ISSUE_A(0,1,1,0); ISSUE_B(0,1,0,0); ISSUE_B(0,1,1,0);
  ISSUE_A(1,0,0,1); ISSUE_A(1,0,1,1); ISSUE_B(1,0,0,1); ISSUE_B(1,0,1,1);
  asm volatile("s_waitcnt vmcnt(4)" ::: "memory");
  BAR();

  for (int u=0; u<NKT; ++u){
    const int b  = u & 1, nb = b ^ 1;
    const int bo = b*32768;
    const int kt1 = (u+1 < NKT) ? u+1 : NKT-1;
    const int kt2 = (u+2 < NKT) ? u+2 : NKT-1;
    bf16x8 av[4], bv[4];

    // ---- ph1: kk0, m 0-3 ---------------------------------------------
    #pragma unroll
    for (int n=0;n<4;++n) bv[n] = LDB(bo, 0, wn*64 + n*16 + lr);
    #pragma unroll
    for (int m=0;m<4;++m) av[m] = LDA(bo, 0, wm*128 + m*16 + lr);
    ISSUE_A(kt1,1,0,nb); ISSUE_A(kt1,1,1,nb);
    BAR(); LGKM0();
    __builtin_amdgcn_s_setprio(1);
    #pragma unroll
    for (int m=0;m<4;++m)
      #pragma unroll
      for (int n=0;n<4;++n)
        acc[m][n] = __builtin_amdgcn_mfma_f32_16x16x32_bf16(av[m], bv[n], acc[m][n],0,0,0);
    __builtin_amdgcn_s_setprio(0);
    BAR();

    // ---- ph2: kk0, m 4-7 (bv reused) ---------------------------------
    #pragma unroll
    for (int m=0;m<4;++m) av[m] = LDA(bo, 0, wm*128 + 64 + m*16 + lr);
    ISSUE_B(kt1,1,0,nb); ISSUE_B(kt1,1,1,nb);
    BAR(); LGKM0();
    __builtin_amdgcn_s_setprio(1);
    #pragma unroll
    for (int m=0;m<4;++m)
      #pragma unroll
      for (int n=0;n<4;++n)
        acc[4+m][n] = __builtin_amdgcn_mfma_f32_16x16x32_bf16(av[m], bv[n], acc[4+m][n],0,0,0);
    __builtin_amdgcn_s_setprio(0);
    BAR();

    // ---- ph3: kk1, m 0-3 ---------------------------------------------
    #pragma unroll
    for (int n=0;n<4;++n) bv[n] = LDB(bo, 1, wn*64 + n*16 + lr);
    #pragma unroll
    for (int m=0;m<4;++m) av[m] = LDA(bo, 1, wm*128 + m*16 + lr);
    ISSUE_A(kt2,0,0,b); ISSUE_A(kt2,0,1,b);   // A@kk0 of buf b free after ph2
    BAR(); LGKM0();
    __builtin_amdgcn_s_setprio(1);
    #pragma unroll
    for (int m=0;m<4;++m)
      #pragma unroll
      for (int n=0;n<4;++n)
        acc[m][n] = __builtin_amdgcn_mfma_f32_16x16x32_bf16(av[m], bv[n], acc[m][n],0,0,0);
    __builtin_amdgcn_s_setprio(0);
    BAR();

    // ---- ph4: kk1, m 4-7 ---------------------------------------------
    #pragma unroll
    for (int m=0;m<4;++m) av[m] = LDA(bo, 1, wm*128 + 64 + m*16 + lr);
    ISSUE_B(kt2,0,0,b); ISSUE_B(kt2,0,1,b);   // B@kk0 of buf b free after ph1
    BAR(); LGKM0();
    __builtin_amdgcn_s_setprio(1);
    #pragma unroll
    for (int m=0;m<4;++m)
      #pragma unroll
      for (int n=0;n<4;++n)
        acc[4+m][n] = __builtin_amdgcn_mfma_f32_16x16x32_bf16(av[m], bv[n], acc[4+m][n],0,0,0);
    __builtin_amdgcn_s_setprio(0);
    asm volatile("s_waitcnt vmcnt(4)" ::: "memory");  // next K-tile fully landed
    BAR();
  }

  asm volatile("s_waitcnt vmcnt(0)" ::: "memory");    // drain tail prefetches
  __syncthreads();                                    // before LDS reuse

  // epilogue: d = sqrt(max(fa + mb - 2ab, 0)); min/argmin per 128-col half.
  // C/D frag layout: col = lane&15, row = (lane>>4)*4 + reg
  const int rowbase = nt*256 + wm*128;
  const int colbase = mt*256 + wn*64;
  float mnv[4];
  #pragma unroll
  for (int n=0;n<4;++n) mnv[n] = mn[colbase + n*16 + lr];
  float* smf = (float*)lds;               // [4][256]
  int*   sii = (int*)((char*)lds + 4096); // [4][256]
  #pragma unroll
  for (int m=0;m<8;++m){
    float mv[4]; int mi[4];
    #pragma unroll
    for (int r=0;r<4;++r){
      float fa = fn[rowbase + m*16 + lk*4 + r];
      mv[r] = FINF; mi[r] = 0x7fffffff;
      #pragma unroll
      for (int n=0;n<4;++n){
        int ci = colbase + n*16 + lr;
        float d2 = fa + mnv[n] - 2.0f*acc[m][n][r];
        float d = sqrtf(fmaxf(d2, 0.0f));
        if (d < mv[r]){ mv[r] = d; mi[r] = ci; }
      }
    }
    #pragma unroll
    for (int msk=1; msk<16; msk<<=1){
      #pragma unroll
      for (int r=0;r<4;++r){
        float ov = __shfl_xor(mv[r], msk);
        int   oi = __shfl_xor(mi[r], msk);
        if (ov < mv[r] || (ov == mv[r] && oi < mi[r])){ mv[r]=ov; mi[r]=oi; }
      }
    }
    if (lr == 0){
      #pragma unroll
      for (int r=0;r<4;++r){
        int rl = wm*128 + m*16 + lk*4 + r;
        smf[wn*256 + rl] = mv[r];
        sii[wn*256 + rl] = mi[r];
      }
    }
  }
  __syncthreads();
  if (tid < 256){
    // halves {wn 0,1} -> 128-col tile 2mt ; {wn 2,3} -> 2mt+1
    float va = smf[tid];       int ia = sii[tid];
    float v1 = smf[256+tid];   int i1 = sii[256+tid];
    if (v1 < va || (v1==va && i1<ia)){ va=v1; ia=i1; }
    float vb = smf[512+tid];   int ib = sii[512+tid];
    float v3 = smf[768+tid];   int i3 = sii[768+tid];
    if (v3 < vb || (v3==vb && i3<ib)){ vb=v3; ib=i3; }
    size_t o = (size_t)(nt*256 + tid)*NMT;
    pmin[o + 2*mt]   = va; pidx[o + 2*mt]   = ia;
    pmin[o + 2*mt+1] = vb; pidx[o + 2*mt+1] = ib;
  }
#undef ISSUE_A
#undef ISSUE_B
#undef LDA
#undef LDB
#undef BAR
#undef LGKM0
}

// ---------------------------------------------------------------------------
// 3) refine: exact fp32 distance for candidates within band of bf16 min
//    -> exact nn_dists / nn_indices (selection-exact vs reference).
// ---------------------------------------------------------------------------
__global__ __launch_bounds__(256) void refine_k(const float* __restrict__ feat,
                                                const float* __restrict__ memf,
                                                const float* __restrict__ fn,
                                                const float* __restrict__ mn,
                                                const float* __restrict__ pmin,
                                                const int* __restrict__ pidx,
                                                float* __restrict__ nnd,
                                                int* __restrict__ nni){
  int wid = threadIdx.x>>6, lane = threadIdx.x&63;
  int row = blockIdx.x*4 + wid;
  const float* pm = pmin + (size_t)row*NMT;
  const int*   pi = pidx + (size_t)row*NMT;
  float v0 = pm[lane], v1 = pm[64+lane];
  float mv = fminf(v0, v1);
  #pragma unroll
  for (int m=32;m;m>>=1) mv = fminf(mv, __shfl_xor(mv, m));
  float band = mv + 0.02f;   // covers bf16-GEMM error (~16 sigma)
  unsigned long long b0 = __ballot(v0 <= band);
  unsigned long long b1 = __ballot(v1 <= band);

  float fr[24];
  const float* f = feat + (size_t)row*C_DIM;
  #pragma unroll
  for (int i=0;i<6;++i){
    float4 t = *(const float4*)(f + i*256 + lane*4);
    fr[i*4+0]=t.x; fr[i*4+1]=t.y; fr[i*4+2]=t.z; fr[i*4+3]=t.w;
  }
  float fa = fn[row];
  float bd = FINF; int bi = 0x7fffffff;
  while (b0 | b1){
    int t;
    if (b0){ t = __ffsll(b0)-1; b0 &= b0-1; }
    else   { t = 64 + __ffsll(b1)-1; b1 &= b1-1; }
    int cidx = pi[t];
    const float* mrow = memf + (size_t)cidx*C_DIM;
    float acc = 0.f;
    #pragma unroll
    for (int i=0;i<6;++i){
      float4 m4 = *(const float4*)(mrow + i*256 + lane*4);
      acc += fr[i*4+0]*m4.x + fr[i*4+1]*m4.y + fr[i*4+2]*m4.z + fr[i*4+3]*m4.w;
    }
    #pragma unroll
    for (int m=32;m;m>>=1) acc += __shfl_xor(acc, m);
    float d = sqrtf(fmaxf(fa + mn[cidx] - 2.0f*acc, 0.f));
    if (d < bd || (d == bd && cidx < bi)){ bd = d; bi = cidx; }
  }
  if (lane==0){ nnd[row]=bd; nni[row]=bi; }
}

// ---------------------------------------------------------------------------
// 4) amap[b] = W ps[b] W^T (separable; exact fp32). WT computed inline
//    per block (cheap: 25-iter loop per thread) -- build_WT launch removed.
// ---------------------------------------------------------------------------
__global__ __launch_bounds__(256) void amap_k(const float* __restrict__ nnd,
                                              float* __restrict__ out){
  __shared__ float ps[256];
  __shared__ float wt[16*256];
  __shared__ float tmp[16*256];
  int b = blockIdx.x, yc = blockIdx.y, t = threadIdx.x;
  ps[t] = nnd[b*256 + t];
  // inline WT: composite (gaussian-zero-pad o bilinear-halfpixel), col y = t
  {
    float g[25]; float Z = 0.f;
    #pragma unroll
    for (int k=0;k<25;++k){ float x=(float)(k-12)*0.25f; g[k]=expf(-0.5f*x*x); Z+=g[k]; }
    float acc16[16];
    #pragma unroll
    for (int i=0;i<16;++i) acc16[i]=0.f;
    for (int dy=0; dy<25; ++dy){
      int yy = t - 12 + dy;
      if (yy < 0 || yy > 255) continue;
      float gg = g[dy]/Z;
      float src = ((float)yy + 0.5f)*0.0625f - 0.5f;
      int i0 = (int)floorf(src);
      float fz = src - (float)i0;
      if (i0 < 0){ i0 = 0; fz = 0.f; }
      else if (i0 >= 15){ i0 = 15; fz = 0.f; }
      acc16[i0] += gg*(1.f-fz);
      if (fz > 0.f) acc16[i0+1] += gg*fz;
    }
    #pragma unroll
    for (int i=0;i<16;++i) wt[i*256+t] = acc16[i];
  }
  __syncthreads();
  #pragma unroll
  for (int i=0;i<16;++i){
    float s=0.f;
    #pragma unroll
    for (int j=0;j<16;++j) s += wt[j*256+t]*ps[i*16+j];
    tmp[i*256+t]=s;
  }
  __syncthreads();
  float* ob = out + ((size_t)b<<16) + yc*32*256 + t;
  for (int yy=0; yy<32; ++yy){
    int y = yc*32+yy;
    float s=0.f;
    #pragma unroll
    for (int i=0;i<16;++i) s += wt[i*256+y]*tmp[i*256+t];
    ob[(size_t)yy*256] = s;
  }
}

// ---------------------------------------------------------------------------
// 5) per-batch argmax of patch scores -> s_star, m_star_idx
// ---------------------------------------------------------------------------
__global__ void argmax_k(const float* __restrict__ nnd, const int* __restrict__ nni,
                         float* __restrict__ sstar, int* __restrict__ midx){
  int b=blockIdx.x, t=threadIdx.x, lane=t&63, wid=t>>6;
  float v = nnd[b*256+t]; int i=t;
  #pragma unroll
  for (int m=1;m<64;m<<=1){
    float ov=__shfl_xor(v,m); int oi=__shfl_xor(i,m);
    if (ov > v || (ov==v && oi<i)){ v=ov; i=oi; }
  }
  __shared__ float sv[4]; __shared__ int si[4];
  if (lane==0){ sv[wid]=v; si[wid]=i; }
  __syncthreads();
  if (t==0){
    for (int w=1;w<4;++w){ if (sv[w]>v || (sv[w]==v && si[w]<i)){ v=sv[w]; i=si[w]; } }
    sstar[b]=v; midx[b]=nni[b*256+i];
  }
}

// ---------------------------------------------------------------------------
// 6) m_dists: 32 m_star vectors (bf16, staged in LDS) vs all memory rows.
//    ILP restructure: 3-way partial accumulation (breaks 24-FMA dep chain),
//    two s-values per iteration (2 independent shuffle-reduce chains).
// ---------------------------------------------------------------------------
__global__ __launch_bounds__(256) void mdist_k(const u16* __restrict__ mb,
                                               const float* __restrict__ mn,
                                               const int* __restrict__ midx,
                                               float* __restrict__ dmat){
  __shared__ u16 ms[16*C_DIM];       // 48 KiB: stage 16 m_stars per half
  __shared__ int sidx[32]; __shared__ float snrm[32];
  int t = threadIdx.x;
  if (t < 32){ int r = midx[t]; sidx[t]=r; snrm[t]=mn[r]; }
  int wid=t>>6, lane=t&63;
  for (int h=0; h<2; ++h){
    __syncthreads();
    for (int c=t; c<3072; c+=256){     // 16 rows x 192 x 16B chunks
      int s = c/192, o = c - s*192;
      *(u16x8*)(&ms[s*C_DIM + o*8]) = *(const u16x8*)(mb + (size_t)sidx[h*16+s]*C_DIM + o*8);
    }
    __syncthreads();
    for (int v=0; v<16; ++v){
      int m = blockIdx.x*64 + wid*16 + v;
      const u16* row = mb + (size_t)m*C_DIM;
      float rf[24];
      #pragma unroll
      for (int i=0;i<3;++i){
        u16x8 rv = *(const u16x8*)(row + i*512 + lane*8);
        #pragma unroll
        for (int j=0;j<8;++j) rf[i*8+j] = bf2f(rv[j]);
      }
      float mnv = mn[m];
      for (int s=0;s<16;s+=2){
        float pa0=0.f, pa1=0.f, pa2=0.f;     // s   : 3 independent partials
        float pb0=0.f, pb1=0.f, pb2=0.f;     // s+1
        #pragma unroll
        for (int i=0;i<3;++i){
          u16x8 wa = *(const u16x8*)(&ms[(s  )*C_DIM + i*512 + lane*8]);
          u16x8 wb = *(const u16x8*)(&ms[(s+1)*C_DIM + i*512 + lane*8]);
          float a0=0.f, b0=0.f;
          #pragma unroll
          for (int j=0;j<8;++j){
            a0 += rf[i*8+j]*bf2f(wa[j]);
            b0 += rf[i*8+j]*bf2f(wb[j]);
          }
          if (i==0){ pa0=a0; pb0=b0; } else if (i==1){ pa1=a0; pb1=b0; } else { pa2=a0; pb2=b0; }
        }
        float accA = pa0+pa1+pa2, accB = pb0+pb1+pb2;
        #pragma unroll
        for (int msk=32;msk;msk>>=1){
          accA += __shfl_xor(accA, msk);
          accB += __shfl_xor(accB, msk);
        }
        if (lane==0){
          dmat[(size_t)(h*16+s  )*M_MEM + m] = sqrtf(fmaxf(snrm[h*16+s  ] + mnv - 2.0f*accA, 0.f));
          dmat[(size_t)(h*16+s+1)*M_MEM + m] = sqrtf(fmaxf(snrm[h*16+s+1] + mnv - 2.0f*accB, 0.f));
        }
      }
    }
  }
}

// ---------------------------------------------------------------------------
// 7) per-batch top-10 smallest distances -> reweighted score (parallel merge)
// ---------------------------------------------------------------------------
__device__ __forceinline__ void top10_scan(const float* src, int n, float* tp){
  #pragma unroll
  for (int i=0;i<10;++i) tp[i]=FINF;
  for (int c=0;c<n;++c){
    float v=src[c];
    if (v < tp[9]){
      #pragma unroll
      for (int j=0;j<10;++j){ float lo=fminf(tp[j],v); v=fmaxf(tp[j],v); tp[j]=lo; }
    }
  }
}

__global__ __launch_bounds__(256) void score_k(const float* __restrict__ dmat,
                                               const float* __restrict__ sstar,
                                               float* __restrict__ out){
  int b=blockIdx.x, t=threadIdx.x;
  float top[10];
  #pragma unroll
  for (int i=0;i<10;++i) top[i]=FINF;
  for (int i=0;i<64;++i){
    float v = dmat[(size_t)b*M_MEM + i*256 + t];
    if (v < top[9]){
      #pragma unroll
      for (int j=0;j<10;++j){ float lo=fminf(top[j],v); v=fmaxf(top[j],v); top[j]=lo; }
    }
  }
  __shared__ float cand[2560];
  __shared__ float l1[640];
  __shared__ float l2[160];
  __shared__ float l3[40];
  #pragma unroll
  for (int i=0;i<10;++i) cand[t*10+i]=top[i];
  __syncthreads();
  if (t < 64){
    float tp[10]; top10_scan(&cand[t*40], 40, tp);
    #pragma unroll
    for (int i=0;i<10;++i) l1[t*10+i]=tp[i];
  }
  __syncthreads();
  if (t < 16){
    float tp[10]; top10_scan(&l1[t*40], 40, tp);
    #pragma unroll
    for (int i=0;i<10;++i) l2[t*10+i]=tp[i];
  }
  __syncthreads();
  if (t < 4){
    float tp[10]; top10_scan(&l2[t*40], 40, tp);
    #pragma unroll
    for (int i=0;i<10;++i) l3[t*10+i]=tp[i];
  }
  __syncthreads();
  if (t==0){
    float tp[10]; top10_scan(l3, 40, tp);
    // drop tp[0] (self); w = 1 - exp(d1)/sum = 1 - 1/sum(exp(di-d1))
    float d1 = tp[1];
    float ssum = 0.f;
    #pragma unroll
    for (int i=1;i<10;++i) ssum += expf(tp[i]-d1);
    out[b] = (1.0f - 1.0f/ssum) * sstar[b];
  }
}

// ---------------------------------------------------------------------------
extern "C" void kernel_launch(void* const* d_in, const int* in_sizes, int n_in,
                              void* d_out, int out_size, void* d_ws, size_t ws_size,
                              hipStream_t stream){
  const float* feat = (const float*)d_in[0];
  const float* memf = (const float*)d_in[1];
  float* out = (float*)d_out;
  char* ws = (char*)d_ws;

  size_t o_fb = 0;
  size_t o_mb = o_fb + (size_t)N_FEAT*C_DIM*2;
  size_t o_fn = o_mb + (size_t)M_MEM*C_DIM*2;
  size_t o_mn = o_fn + (size_t)N_FEAT*4;
  size_t o_pv = o_mn + (size_t)M_MEM*4;
  size_t o_pi = o_pv + (size_t)N_FEAT*NMT*4;
  size_t o_nd = o_pi + (size_t)N_FEAT*NMT*4;
  size_t o_ni = o_nd + (size_t)N_FEAT*4;
  size_t o_ss = o_ni + (size_t)N_FEAT*4;
  size_t o_mi = o_ss + (size_t)NBATCH*4;
  size_t o_dm = o_mi + (size_t)NBATCH*4;
  size_t need = o_dm + (size_t)NBATCH*M_MEM*4;
  if (ws_size < need) return;

  u16*   fb  = (u16*)(ws+o_fb);
  u16*   mb  = (u16*)(ws+o_mb);
  float* fn  = (float*)(ws+o_fn);
  float* mn  = (float*)(ws+o_mn);
  float* pv  = (float*)(ws+o_pv);
  int*   pi  = (int*)(ws+o_pi);
  float* nd  = (float*)(ws+o_nd);
  int*   ni  = (int*)(ws+o_ni);
  float* ss  = (float*)(ws+o_ss);
  int*   mi  = (int*)(ws+o_mi);
  float* dm  = (float*)(ws+o_dm);

  conv_norm_k<<<N_FEAT/4, 256, 0, stream>>>(feat, fb, fn);
  conv_norm_k<<<M_MEM/4, 256, 0, stream>>>(memf, mb, mn);
  dist256_k<<<2048, 512, 0, stream>>>(fb, mb, fn, mn, pv, pi);
  refine_k<<<N_FEAT/4, 256, 0, stream>>>(feat, memf, fn, mn, pv, pi, nd, ni);
  argmax_k<<<NBATCH, 256, 0, stream>>>(nd, ni, ss, mi);
  mdist_k<<<M_MEM/64, 256, 0, stream>>>(mb, mn, mi, dm);
  amap_k<<<dim3(NBATCH, 8), 256, 0, stream>>>(nd, out + 32);
  score_k<<<NBATCH, 256, 0, stream>>>(dm, ss, out);
}

// Round 11
// 704.431 us; speedup vs baseline: 3.5667x; 1.1028x over previous
//
#include <hip/hip_runtime.h>

typedef unsigned short u16;
typedef __bf16 bf16x8 __attribute__((ext_vector_type(8)));
typedef float f32x4 __attribute__((ext_vector_type(4)));
typedef u16 u16x8 __attribute__((ext_vector_type(8)));
typedef u16 u16x4 __attribute__((ext_vector_type(4)));

#define N_FEAT 8192
#define M_MEM 16384
#define C_DIM 1536
#define NBATCH 32
#define NKT 24            // 1536/64 K-tiles (BK=64)
#define NMT 128           // 16384/128 memory tiles (two per 256-col block)
#define FINF 3.4e38f

__device__ __forceinline__ u16 f2bf(float x){           // RTNE fp32->bf16
  unsigned u = __float_as_uint(x);
  u += 0x7fffu + ((u >> 16) & 1u);
  return (u16)(u >> 16);
}
__device__ __forceinline__ float bf2f(u16 h){
  return __uint_as_float(((unsigned)h) << 16);
}

#define GLDS16(g, l) __builtin_amdgcn_global_load_lds( \
    (const __attribute__((address_space(1))) void*)(g), \
    (__attribute__((address_space(3))) void*)(l), 16, 0, 0)

// ---------------------------------------------------------------------------
// 1) fp32 -> bf16 copy + exact fp32 row norms for BOTH inputs (one launch).
//    1 wave per row, 4 rows/block; rows 0..8191 = feat, rest = memory bank.
// ---------------------------------------------------------------------------
__global__ __launch_bounds__(256) void conv_both_k(const float* __restrict__ feat,
                                                   const float* __restrict__ memf,
                                                   u16* __restrict__ fb,
                                                   u16* __restrict__ mb,
                                                   float* __restrict__ fn,
                                                   float* __restrict__ mn){
  int row  = blockIdx.x*4 + (threadIdx.x>>6);
  int lane = threadIdx.x & 63;
  const float* in; u16* ob; float* nrm; int r;
  if (row < N_FEAT){ in = feat; ob = fb; nrm = fn; r = row; }
  else             { in = memf; ob = mb; nrm = mn; r = row - N_FEAT; }
  const float* src = in + (size_t)r*C_DIM;
  u16* o = ob + (size_t)r*C_DIM;
  float s = 0.f;
  #pragma unroll
  for (int i=0;i<6;++i){
    int idx = i*256 + lane*4;
    float4 v = *(const float4*)(src + idx);
    s += v.x*v.x + v.y*v.y + v.z*v.z + v.w*v.w;
    u16x4 u; u.x=f2bf(v.x); u.y=f2bf(v.y); u.z=f2bf(v.z); u.w=f2bf(v.w);
    *(u16x4*)(o + idx) = u;
  }
  #pragma unroll
  for (int m=32;m;m>>=1) s += __shfl_xor(s, m);
  if (lane==0) nrm[r] = s;
}

// ---------------------------------------------------------------------------
// 2) 256x256 bf16 MFMA distance (best-measured schedule: 4-phase lockstep,
//    counted vmcnt, rect XCD remap) + fused min/argmin emitted at 128-col
//    granularity (2 outputs per block). UNCHANGED (control).
// ---------------------------------------------------------------------------
__global__ __launch_bounds__(512, 2) void dist256_k(const u16* __restrict__ fb,
                                                    const u16* __restrict__ mb,
                                                    const float* __restrict__ fn,
                                                    const float* __restrict__ mn,
                                                    float* __restrict__ pmin,
                                                    int* __restrict__ pidx){
  __shared__ u16 lds[65536];          // 128 KiB: 2 bufs x (A 32K + B 32K)
  const int tid = threadIdx.x;
  const int bid = blockIdx.x;
  // XCD-aware 2D remap: co-resident 32 blocks/XCD = 4 nt x 8 mt rectangle.
  const int xcd = bid & 7;
  const int li  = bid >> 3;                     // 0..255 within XCD
  const int nt  = ((li >> 5) << 2) | (li & 3);  // 0..31 feature tile
  const int mt  = (xcd << 3) | ((li >> 2) & 7); // 0..63 memory tile (256-col)
  const int wid = tid >> 6, lane = tid & 63;
  const int wm = wid >> 2, wn = wid & 3;        // 2x4 waves, each 128x64 out
  const int lr = lane & 15, lk = lane >> 4;
  const int slk8 = (lk ^ ((lr >> 1) & 3)) * 8;  // swizzled read chunk (u16 units)
  const int sgc  = (tid & 3) ^ ((tid >> 3) & 3);// pre-swizzled source chunk
  const int arow0 = nt*256, brow0 = mt*256;

  // u16-unit LDS offsets: buf stride 32768, B at +16384, kk at +8192, h at +4096
#define ISSUE_A(kt, kk, h, bb) GLDS16( \
    fb + (size_t)(arow0 + (h)*128 + (tid>>2))*C_DIM + (kt)*64 + (kk)*32 + sgc*8, \
    lds + (bb)*32768 + (kk)*8192 + (h)*4096 + tid*8)
#define ISSUE_B(kt, kk, h, bb) GLDS16( \
    mb + (size_t)(brow0 + (h)*128 + (tid>>2))*C_DIM + (kt)*64 + (kk)*32 + sgc*8, \
    lds + (bb)*32768 + 16384 + (kk)*8192 + (h)*4096 + tid*8)
#define LDA(bo, kk, row) (*(const bf16x8*)(lds + (bo) + (kk)*8192 + (row)*32 + slk8))
#define LDB(bo, kk, row) (*(const bf16x8*)(lds + (bo) + 16384 + (kk)*8192 + (row)*32 + slk8))
#define BAR()   __builtin_amdgcn_s_barrier()
#define LGKM0() asm volatile("s_waitcnt lgkmcnt(0)" ::: "memory")

  f32x4 acc[8][4];
  #pragma unroll
  for (int m=0;m<8;++m)
    #pragma unroll
    for (int n=0;n<4;++n) acc[m][n] = (f32x4){0.f,0.f,0.f,0.f};

  // prologue: K-tile 0 (8 issues) + K-tile 1 kk0 (4 issues); wait K-tile 0.
  ISSUE_A(0,0,0,0); ISSUE_A(0,0,1,0); ISSUE_B(0,0,0,0); ISSUE_B(0,0,1,0);
  ISSUE_A(0,1,0,0); ISSUE_A(0,1,1,0); ISSUE_B(0,1,0,0); ISSUE_B(0,1,1,0);
  ISSUE_A(1,0,0,1); ISSUE_A(1,0,1,1); ISSUE_B(1,0,0,1); ISSUE_B(1,0,1,1);
  asm volatile("s_waitcnt vmcnt(4)" ::: "memory");
  BAR();

  for (int u=0; u<NKT; ++u){
    const int b  = u & 1, nb = b ^ 1;
    const int bo = b*32768;
    const int kt1 = (u+1 < NKT) ? u+1 : NKT-1;
    const int kt2 = (u+2 < NKT) ? u+2 : NKT-1;
    bf16x8 av[4], bv[4];

    // ---- ph1: kk0, m 0-3 ---------------------------------------------
    #pragma unroll
    for (int n=0;n<4;++n) bv[n] = LDB(bo, 0, wn*64 + n*16 + lr);
    #pragma unroll
    for (int m=0;m<4;++m) av[m] = LDA(bo, 0, wm*128 + m*16 + lr);
    ISSUE_A(kt1,1,0,nb); ISSUE_A(kt1,1,1,nb);
    BAR(); LGKM0();
    __builtin_amdgcn_s_setprio(1);
    #pragma unroll
    for (int m=0;m<4;++m)
      #pragma unroll
      for (int n=0;n<4;++n)
        acc[m][n] = __builtin_amdgcn_mfma_f32_16x16x32_bf16(av[m], bv[n], acc[m][n],0,0,0);
    __builtin_amdgcn_s_setprio(0);
    BAR();

    // ---- ph2: kk0, m 4-7 (bv reused) ---------------------------------
    #pragma unroll
    for (int m=0;m<4;++m) av[m] = LDA(bo, 0, wm*128 + 64 + m*16 + lr);
    ISSUE_B(kt1,1,0,nb); ISSUE_B(kt1,1,1,nb);
    BAR(); LGKM0();
    __builtin_amdgcn_s_setprio(1);
    #pragma unroll
    for (int m=0;m<4;++m)
      #pragma unroll
      for (int n=0;n<4;++n)
        acc[4+m][n] = __builtin_amdgcn_mfma_f32_16x16x32_bf16(av[m], bv[n], acc[4+m][n],0,0,0);
    __builtin_amdgcn_s_setprio(0);
    BAR();

    // ---- ph3: kk1, m 0-3 ---------------------------------------------
    #pragma unroll
    for (int n=0;n<4;++n) bv[n] = LDB(bo, 1, wn*64 + n*16 + lr);
    #pragma unroll
    for (int m=0;m<4;++m) av[m] = LDA(bo, 1, wm*128 + m*16 + lr);
    ISSUE_A(kt2,0,0,b); ISSUE_A(kt2,0,1,b);   // A@kk0 of buf b free after ph2
    BAR(); LGKM0();
    __builtin_amdgcn_s_setprio(1);
    #pragma unroll
    for (int m=0;m<4;++m)
      #pragma unroll
      for (int n=0;n<4;++n)
        acc[m][n] = __builtin_amdgcn_mfma_f32_16x16x32_bf16(av[m], bv[n], acc[m][n],0,0,0);
    __builtin_amdgcn_s_setprio(0);
    BAR();

    // ---- ph4: kk1, m 4-7 ---------------------------------------------
    #pragma unroll
    for (int m=0;m<4;++m) av[m] = LDA(bo, 1, wm*128 + 64 + m*16 + lr);
    ISSUE_B(kt2,0,0,b); ISSUE_B(kt2,0,1,b);   // B@kk0 of buf b free after ph1
    BAR(); LGKM0();
    __builtin_amdgcn_s_setprio(1);
    #pragma unroll
    for (int m=0;m<4;++m)
      #pragma unroll
      for (int n=0;n<4;++n)
        acc[4+m][n] = __builtin_amdgcn_mfma_f32_16x16x32_bf16(av[m], bv[n], acc[4+m][n],0,0,0);
    __builtin_amdgcn_s_setprio(0);
    asm volatile("s_waitcnt vmcnt(4)" ::: "memory");  // next K-tile fully landed
    BAR();
  }

  asm volatile("s_waitcnt vmcnt(0)" ::: "memory");    // drain tail prefetches
  __syncthreads();                                    // before LDS reuse

  // epilogue: d = sqrt(max(fa + mb - 2ab, 0)); min/argmin per 128-col half.
  // C/D frag layout: col = lane&15, row = (lane>>4)*4 + reg
  const int rowbase = nt*256 + wm*128;
  const int colbase = mt*256 + wn*64;
  float mnv[4];
  #pragma unroll
  for (int n=0;n<4;++n) mnv[n] = mn[colbase + n*16 + lr];
  float* smf = (float*)lds;               // [4][256]
  int*   sii = (int*)((char*)lds + 4096); // [4][256]
  #pragma unroll
  for (int m=0;m<8;++m){
    float mv[4]; int mi[4];
    #pragma unroll
    for (int r=0;r<4;++r){
      float fa = fn[rowbase + m*16 + lk*4 + r];
      mv[r] = FINF; mi[r] = 0x7fffffff;
      #pragma unroll
      for (int n=0;n<4;++n){
        int ci = colbase + n*16 + lr;
        float d2 = fa + mnv[n] - 2.0f*acc[m][n][r];
        float d = sqrtf(fmaxf(d2, 0.0f));
        if (d < mv[r]){ mv[r] = d; mi[r] = ci; }
      }
    }
    #pragma unroll
    for (int msk=1; msk<16; msk<<=1){
      #pragma unroll
      for (int r=0;r<4;++r){
        float ov = __shfl_xor(mv[r], msk);
        int   oi = __shfl_xor(mi[r], msk);
        if (ov < mv[r] || (ov == mv[r] && oi < mi[r])){ mv[r]=ov; mi[r]=oi; }
      }
    }
    if (lr == 0){
      #pragma unroll
      for (int r=0;r<4;++r){
        int rl = wm*128 + m*16 + lk*4 + r;
        smf[wn*256 + rl] = mv[r];
        sii[wn*256 + rl] = mi[r];
      }
    }
  }
  __syncthreads();
  if (tid < 256){
    // halves {wn 0,1} -> 128-col tile 2mt ; {wn 2,3} -> 2mt+1
    float va = smf[tid];       int ia = sii[tid];
    float v1 = smf[256+tid];   int i1 = sii[256+tid];
    if (v1 < va || (v1==va && i1<ia)){ va=v1; ia=i1; }
    float vb = smf[512+tid];   int ib = sii[512+tid];
    float v3 = smf[768+tid];   int i3 = sii[768+tid];
    if (v3 < vb || (v3==vb && i3<ib)){ vb=v3; ib=i3; }
    size_t o = (size_t)(nt*256 + tid)*NMT;
    pmin[o + 2*mt]   = va; pidx[o + 2*mt]   = ia;
    pmin[o + 2*mt+1] = vb; pidx[o + 2*mt+1] = ib;
  }
#undef ISSUE_A
#undef ISSUE_B
#undef LDA
#undef LDB
#undef BAR
#undef LGKM0
}

// ---------------------------------------------------------------------------
// 3) refine: exact fp32 distance for candidates within band of bf16 min
//    -> exact nn_dists / nn_indices (selection-exact vs reference).
// ---------------------------------------------------------------------------
__global__ __launch_bounds__(256) void refine_k(const float* __restrict__ feat,
                                                const float* __restrict__ memf,
                                                const float* __restrict__ fn,
                                                const float* __restrict__ mn,
                                                const float* __restrict__ pmin,
                                                const int* __restrict__ pidx,
                                                float* __restrict__ nnd,
                                                int* __restrict__ nni){
  int wid = threadIdx.x>>6, lane = threadIdx.x&63;
  int row = blockIdx.x*4 + wid;
  const float* pm = pmin + (size_t)row*NMT;
  const int*   pi = pidx + (size_t)row*NMT;
  float v0 = pm[lane], v1 = pm[64+lane];
  float mv = fminf(v0, v1);
  #pragma unroll
  for (int m=32;m;m>>=1) mv = fminf(mv, __shfl_xor(mv, m));
  float band = mv + 0.02f;   // covers bf16-GEMM error (~16 sigma)
  unsigned long long b0 = __ballot(v0 <= band);
  unsigned long long b1 = __ballot(v1 <= band);

  float fr[24];
  const float* f = feat + (size_t)row*C_DIM;
  #pragma unroll
  for (int i=0;i<6;++i){
    float4 t = *(const float4*)(f + i*256 + lane*4);
    fr[i*4+0]=t.x; fr[i*4+1]=t.y; fr[i*4+2]=t.z; fr[i*4+3]=t.w;
  }
  float fa = fn[row];
  float bd = FINF; int bi = 0x7fffffff;
  while (b0 | b1){
    int t;
    if (b0){ t = __ffsll(b0)-1; b0 &= b0-1; }
    else   { t = 64 + __ffsll(b1)-1; b1 &= b1-1; }
    int cidx = pi[t];
    const float* mrow = memf + (size_t)cidx*C_DIM;
    float acc = 0.f;
    #pragma unroll
    for (int i=0;i<6;++i){
      float4 m4 = *(const float4*)(mrow + i*256 + lane*4);
      acc += fr[i*4+0]*m4.x + fr[i*4+1]*m4.y + fr[i*4+2]*m4.z + fr[i*4+3]*m4.w;
    }
    #pragma unroll
    for (int m=32;m;m>>=1) acc += __shfl_xor(acc, m);
    float d = sqrtf(fmaxf(fa + mn[cidx] - 2.0f*acc, 0.f));
    if (d < bd || (d == bd && cidx < bi)){ bd = d; bi = cidx; }
  }
  if (lane==0){ nnd[row]=bd; nni[row]=bi; }
}

// ---------------------------------------------------------------------------
// 4) amap[b] = W ps[b] W^T (separable; exact fp32). WT computed inline.
// ---------------------------------------------------------------------------
__global__ __launch_bounds__(256) void amap_k(const float* __restrict__ nnd,
                                              float* __restrict__ out){
  __shared__ float ps[256];
  __shared__ float wt[16*256];
  __shared__ float tmp[16*256];
  int b = blockIdx.x, yc = blockIdx.y, t = threadIdx.x;
  ps[t] = nnd[b*256 + t];
  // inline WT: composite (gaussian-zero-pad o bilinear-halfpixel), col y = t
  {
    float g[25]; float Z = 0.f;
    #pragma unroll
    for (int k=0;k<25;++k){ float x=(float)(k-12)*0.25f; g[k]=expf(-0.5f*x*x); Z+=g[k]; }
    float acc16[16];
    #pragma unroll
    for (int i=0;i<16;++i) acc16[i]=0.f;
    for (int dy=0; dy<25; ++dy){
      int yy = t - 12 + dy;
      if (yy < 0 || yy > 255) continue;
      float gg = g[dy]/Z;
      float src = ((float)yy + 0.5f)*0.0625f - 0.5f;
      int i0 = (int)floorf(src);
      float fz = src - (float)i0;
      if (i0 < 0){ i0 = 0; fz = 0.f; }
      else if (i0 >= 15){ i0 = 15; fz = 0.f; }
      acc16[i0] += gg*(1.f-fz);
      if (fz > 0.f) acc16[i0+1] += gg*fz;
    }
    #pragma unroll
    for (int i=0;i<16;++i) wt[i*256+t] = acc16[i];
  }
  __syncthreads();
  #pragma unroll
  for (int i=0;i<16;++i){
    float s=0.f;
    #pragma unroll
    for (int j=0;j<16;++j) s += wt[j*256+t]*ps[i*16+j];
    tmp[i*256+t]=s;
  }
  __syncthreads();
  float* ob = out + ((size_t)b<<16) + yc*32*256 + t;
  for (int yy=0; yy<32; ++yy){
    int y = yc*32+yy;
    float s=0.f;
    #pragma unroll
    for (int i=0;i<16;++i) s += wt[i*256+y]*tmp[i*256+t];
    ob[(size_t)yy*256] = s;
  }
}

// ---------------------------------------------------------------------------
// 5) per-batch argmax of patch scores -> s_star, m_star_idx
// ---------------------------------------------------------------------------
__global__ void argmax_k(const float* __restrict__ nnd, const int* __restrict__ nni,
                         float* __restrict__ sstar, int* __restrict__ midx){
  int b=blockIdx.x, t=threadIdx.x, lane=t&63, wid=t>>6;
  float v = nnd[b*256+t]; int i=t;
  #pragma unroll
  for (int m=1;m<64;m<<=1){
    float ov=__shfl_xor(v,m); int oi=__shfl_xor(i,m);
    if (ov > v || (ov==v && oi<i)){ v=ov; i=oi; }
  }
  __shared__ float sv[4]; __shared__ int si[4];
  if (lane==0){ sv[wid]=v; si[wid]=i; }
  __syncthreads();
  if (t==0){
    for (int w=1;w<4;++w){ if (sv[w]>v || (sv[w]==v && si[w]<i)){ v=sv[w]; i=si[w]; } }
    sstar[b]=v; midx[b]=nni[b*256+i];
  }
}

// ---------------------------------------------------------------------------
// 6) m_dists: 32 m_star vectors (bf16, staged in LDS) vs all memory rows.
//    grid 1024 (16 rows/block, 48 KiB LDS -> 3 blocks/CU TLP) + 3-way
//    partial accumulation + two s-values per iteration.
// ---------------------------------------------------------------------------
__global__ __launch_bounds__(256) void mdist_k(const u16* __restrict__ mb,
                                               const float* __restrict__ mn,
                                               const int* __restrict__ midx,
                                               float* __restrict__ dmat){
  __shared__ u16 ms[16*C_DIM];       // 48 KiB: stage 16 m_stars per half
  __shared__ int sidx[32]; __shared__ float snrm[32];
  int t = threadIdx.x;
  if (t < 32){ int r = midx[t]; sidx[t]=r; snrm[t]=mn[r]; }
  int wid=t>>6, lane=t&63;
  for (int h=0; h<2; ++h){
    __syncthreads();
    for (int c=t; c<3072; c+=256){     // 16 rows x 192 x 16B chunks
      int s = c/192, o = c - s*192;
      *(u16x8*)(&ms[s*C_DIM + o*8]) = *(const u16x8*)(mb + (size_t)sidx[h*16+s]*C_DIM + o*8);
    }
    __syncthreads();
    for (int v=0; v<4; ++v){
      int m = blockIdx.x*16 + wid*4 + v;
      const u16* row = mb + (size_t)m*C_DIM;
      float rf[24];
      #pragma unroll
      for (int i=0;i<3;++i){
        u16x8 rv = *(const u16x8*)(row + i*512 + lane*8);
        #pragma unroll
        for (int j=0;j<8;++j) rf[i*8+j] = bf2f(rv[j]);
      }
      float mnv = mn[m];
      for (int s=0;s<16;s+=2){
        float pa0=0.f, pa1=0.f, pa2=0.f;     // s   : 3 independent partials
        float pb0=0.f, pb1=0.f, pb2=0.f;     // s+1
        #pragma unroll
        for (int i=0;i<3;++i){
          u16x8 wa = *(const u16x8*)(&ms[(s  )*C_DIM + i*512 + lane*8]);
          u16x8 wb = *(const u16x8*)(&ms[(s+1)*C_DIM + i*512 + lane*8]);
          float a0=0.f, b0=0.f;
          #pragma unroll
          for (int j=0;j<8;++j){
            a0 += rf[i*8+j]*bf2f(wa[j]);
            b0 += rf[i*8+j]*bf2f(wb[j]);
          }
          if (i==0){ pa0=a0; pb0=b0; } else if (i==1){ pa1=a0; pb1=b0; } else { pa2=a0; pb2=b0; }
        }
        float accA = pa0+pa1+pa2, accB = pb0+pb1+pb2;
        #pragma unroll
        for (int msk=32;msk;msk>>=1){
          accA += __shfl_xor(accA, msk);
          accB += __shfl_xor(accB, msk);
        }
        if (lane==0){
          dmat[(size_t)(h*16+s  )*M_MEM + m] = sqrtf(fmaxf(snrm[h*16+s  ] + mnv - 2.0f*accA, 0.f));
          dmat[(size_t)(h*16+s+1)*M_MEM + m] = sqrtf(fmaxf(snrm[h*16+s+1] + mnv - 2.0f*accB, 0.f));
        }
      }
    }
  }
}

// ---------------------------------------------------------------------------
// 7) per-batch top-10 smallest distances -> reweighted score (parallel merge)
// ---------------------------------------------------------------------------
__device__ __forceinline__ void top10_scan(const float* src, int n, float* tp){
  #pragma unroll
  for (int i=0;i<10;++i) tp[i]=FINF;
  for (int c=0;c<n;++c){
    float v=src[c];
    if (v < tp[9]){
      #pragma unroll
      for (int j=0;j<10;++j){ float lo=fminf(tp[j],v); v=fmaxf(tp[j],v); tp[j]=lo; }
    }
  }
}

__global__ __launch_bounds__(256) void score_k(const float* __restrict__ dmat,
                                               const float* __restrict__ sstar,
                                               float* __restrict__ out){
  int b=blockIdx.x, t=threadIdx.x;
  float top[10];
  #pragma unroll
  for (int i=0;i<10;++i) top[i]=FINF;
  for (int i=0;i<64;++i){
    float v = dmat[(size_t)b*M_MEM + i*256 + t];
    if (v < top[9]){
      #pragma unroll
      for (int j=0;j<10;++j){ float lo=fminf(top[j],v); v=fmaxf(top[j],v); top[j]=lo; }
    }
  }
  __shared__ float cand[2560];
  __shared__ float l1[640];
  __shared__ float l2[160];
  __shared__ float l3[40];
  #pragma unroll
  for (int i=0;i<10;++i) cand[t*10+i]=top[i];
  __syncthreads();
  if (t < 64){
    float tp[10]; top10_scan(&cand[t*40], 40, tp);
    #pragma unroll
    for (int i=0;i<10;++i) l1[t*10+i]=tp[i];
  }
  __syncthreads();
  if (t < 16){
    float tp[10]; top10_scan(&l1[t*40], 40, tp);
    #pragma unroll
    for (int i=0;i<10;++i) l2[t*10+i]=tp[i];
  }
  __syncthreads();
  if (t < 4){
    float tp[10]; top10_scan(&l2[t*40], 40, tp);
    #pragma unroll
    for (int i=0;i<10;++i) l3[t*10+i]=tp[i];
  }
  __syncthreads();
  if (t==0){
    float tp[10]; top10_scan(l3, 40, tp);
    // drop tp[0] (self); w = 1 - exp(d1)/sum = 1 - 1/sum(exp(di-d1))
    float d1 = tp[1];
    float ssum = 0.f;
    #pragma unroll
    for (int i=1;i<10;++i) ssum += expf(tp[i]-d1);
    out[b] = (1.0f - 1.0f/ssum) * sstar[b];
  }
}

// ---------------------------------------------------------------------------
extern "C" void kernel_launch(void* const* d_in, const int* in_sizes, int n_in,
                              void* d_out, int out_size, void* d_ws, size_t ws_size,
                              hipStream_t stream){
  const float* feat = (const float*)d_in[0];
  const float* memf = (const float*)d_in[1];
  float* out = (float*)d_out;
  char* ws = (char*)d_ws;

  size_t o_fb = 0;
  size_t o_mb = o_fb + (size_t)N_FEAT*C_DIM*2;
  size_t o_fn = o_mb + (size_t)M_MEM*C_DIM*2;
  size_t o_mn = o_fn + (size_t)N_FEAT*4;
  size_t o_pv = o_mn + (size_t)M_MEM*4;
  size_t o_pi = o_pv + (size_t)N_FEAT*NMT*4;
  size_t o_nd = o_pi + (size_t)N_FEAT*NMT*4;
  size_t o_ni = o_nd + (size_t)N_FEAT*4;
  size_t o_ss = o_ni + (size_t)N_FEAT*4;
  size_t o_mi = o_ss + (size_t)NBATCH*4;
  size_t o_dm = o_mi + (size_t)NBATCH*4;
  size_t need = o_dm + (size_t)NBATCH*M_MEM*4;
  if (ws_size < need) return;

  u16*   fb  = (u16*)(ws+o_fb);
  u16*   mb  = (u16*)(ws+o_mb);
  float* fn  = (float*)(ws+o_fn);
  float* mn  = (float*)(ws+o_mn);
  float* pv  = (float*)(ws+o_pv);
  int*   pi  = (int*)(ws+o_pi);
  float* nd  = (float*)(ws+o_nd);
  int*   ni  = (int*)(ws+o_ni);
  float* ss  = (float*)(ws+o_ss);
  int*   mi  = (int*)(ws+o_mi);
  float* dm  = (float*)(ws+o_dm);

  conv_both_k<<<(N_FEAT+M_MEM)/4, 256, 0, stream>>>(feat, memf, fb, mb, fn, mn);
  dist256_k<<<2048, 512, 0, stream>>>(fb, mb, fn, mn, pv, pi);
  refine_k<<<N_FEAT/4, 256, 0, stream>>>(feat, memf, fn, mn, pv, pi, nd, ni);
  argmax_k<<<NBATCH, 256, 0, stream>>>(nd, ni, ss, mi);
  mdist_k<<<M_MEM/16, 256, 0, stream>>>(mb, mn, mi, dm);
  amap_k<<<dim3(NBATCH, 8), 256, 0, stream>>>(nd, out + 32);
  score_k<<<NBATCH, 256, 0, stream>>>(dm, ss, out);
}